// Round 5
// baseline (709.241 us; speedup 1.0000x reference)
//
#include <hip/hip_runtime.h>
#include <math.h>
#include <stdint.h>

#define HW 16777216u
#define COL_CAP  65536u              // tie-bucket collection cap, per side
#define LIST_CAP (4u*1024u*1024u)    // candidate list cap, per side
#define WIN_CAP  8192u

// ---------------- threefry2x32 (JAX-compatible, 20 rounds) ----------------
__host__ __device__ inline uint32_t tf_rotl(uint32_t x, int n){ return (x<<n)|(x>>(32-n)); }

__host__ __device__ inline void threefry2x32(uint32_t k0, uint32_t k1, uint32_t x0, uint32_t x1,
                                             uint32_t &o0, uint32_t &o1){
  uint32_t ks2 = k0 ^ k1 ^ 0x1BD11BDAu;
  x0 += k0; x1 += k1;
#define TF_R4(a,b,c,d) \
  x0 += x1; x1 = tf_rotl(x1,(a)); x1 ^= x0; \
  x0 += x1; x1 = tf_rotl(x1,(b)); x1 ^= x0; \
  x0 += x1; x1 = tf_rotl(x1,(c)); x1 ^= x0; \
  x0 += x1; x1 = tf_rotl(x1,(d)); x1 ^= x0;
  TF_R4(13,15,26,6)  x0 += k1;  x1 += ks2 + 1u;
  TF_R4(17,29,16,24) x0 += ks2; x1 += k0  + 2u;
  TF_R4(13,15,26,6)  x0 += k0;  x1 += k1  + 3u;
  TF_R4(17,29,16,24) x0 += k1;  x1 += ks2 + 4u;
  TF_R4(13,15,26,6)  x0 += ks2; x1 += k0  + 5u;
#undef TF_R4
  o0 = x0; o1 = x1;
}

// order-preserving uint mapping for floats (ascending)
__device__ __forceinline__ uint32_t okey(float f){
  uint32_t b = __float_as_uint(f);
  return (b & 0x80000000u) ? ~b : (b | 0x80000000u);
}
__device__ __forceinline__ float inv_okey(uint32_t k){
  uint32_t b = (k & 0x80000000u) ? (k & 0x7FFFFFFFu) : ~k;
  return __uint_as_float(b);
}

// value-domain bins (monotone in okey for v>=0). cam uniform [0,1] -> ~4096/bin.
__device__ __forceinline__ unsigned vbin(float v){
  unsigned b = (unsigned)(v * 4096.0f);
  return b > 4095u ? 4095u : b;
}
// score-domain bins: scores lie in ~[-3.7, 16). monotone affine map.
__device__ __forceinline__ unsigned sbin(float s){
  float t = (s + 4.0f) * 204.8f;
  int b = (int)t;
  b = b < 0 ? 0 : (b > 4095 ? 4095 : b);
  return (unsigned)b;
}

// wave-aggregated append: one atomic per wave (only used on low-rate paths)
__device__ __forceinline__ unsigned wave_reserve(unsigned* cnt){
  unsigned long long m = __ballot(1);
  unsigned lane = threadIdx.x & 63u;
  unsigned leader = (unsigned)__ffsll((unsigned long long)m) - 1u;
  unsigned prefix = (unsigned)__popcll(m & ((1ull << lane) - 1ull));
  unsigned base = 0u;
  if (lane == leader) base = atomicAdd(cnt, (unsigned)__popcll(m));
  base = __shfl(base, (int)leader, 64);
  return base + prefix;
}

// block-wide 2-channel scan (round-3 note: ONE global atomic per block per
// channel — per-wave contended atomics measured 11ns each, catastrophic)
__device__ void block_scan2(unsigned a, unsigned b, unsigned* offA, unsigned* offB,
                            unsigned* totA, unsigned* totB){
  __shared__ unsigned sA[256], sB[256];
  unsigned t = threadIdx.x;
  sA[t] = a; sB[t] = b;
  __syncthreads();
  for (int d = 1; d < 256; d <<= 1){
    unsigned xa = (t >= (unsigned)d) ? sA[t-d] : 0u;
    unsigned xb = (t >= (unsigned)d) ? sB[t-d] : 0u;
    __syncthreads();
    sA[t] += xa; sB[t] += xb;
    __syncthreads();
  }
  *offA = sA[t] - a; *offB = sB[t] - b;
  *totA = sA[255];   *totB = sB[255];
}

// st layout (u32): [0]=sum(roi)
//  fg_cand base 8 / bg_cand 16 / fg_score 24 / bg_score 32:
//    +0 bin, +1 rem, +4 T(okey), +5 cut_idx
//  [48],[49] list counts; [50],[51] winner counts
// ccnt: [0],[1] collection counts (reused per round)

// --------- pass 1: packed value-hist (fg hi16, bg lo16) + roi sum ---------
__global__ void k_hist_val(const float4* __restrict__ cam4, const int4* __restrict__ roi4,
                           unsigned* __restrict__ h1a, unsigned* __restrict__ h1b,
                           unsigned* __restrict__ st){
  __shared__ unsigned hp[4096];
  __shared__ unsigned ssum;
  for (int j = threadIdx.x; j < 4096; j += 256) hp[j] = 0u;
  if (threadIdx.x == 0) ssum = 0u;
  __syncthreads();
  unsigned base = blockIdx.x * 8192u;   // float4 units; block covers 32768 elems
  unsigned rs = 0u;
  for (int j = 0; j < 32; j++){
    unsigned u = base + threadIdx.x + (unsigned)j*256u;
    float4 c = cam4[u]; int4 r = roi4[u];
#define HV(cc, rr) { unsigned b = vbin((cc) + 1e-8f); \
    atomicAdd(&hp[b], (rr) ? 0x10001u : 1u); rs += (unsigned)(rr); }
    HV(c.x, r.x) HV(c.y, r.y) HV(c.z, r.z) HV(c.w, r.w)
#undef HV
  }
  atomicAdd(&ssum, rs);
  __syncthreads();
  for (int j = threadIdx.x; j < 4096; j += 256){
    unsigned p = hp[j];
    if (p){
      unsigned fa = p >> 16, fb = p & 0xFFFFu;
      if (fa) atomicAdd(&h1a[j], fa);
      if (fb) atomicAdd(&h1b[j], fb);
    }
  }
  if (threadIdx.x == 0) atomicAdd(&st[0], ssum);
}

// --------------- block-cooperative select over 4096-bin hist --------------
__device__ void block_select4096(const unsigned* __restrict__ h, unsigned n, bool top,
                                 unsigned* out_bin, unsigned* out_rem){
  __shared__ unsigned csum[256];
  __shared__ unsigned sb, sr;
  unsigned t = threadIdx.x;
  unsigned s = 0u;
  #pragma unroll
  for (int j = 0; j < 16; j++) s += h[t*16 + j];
  csum[t] = s;
  __syncthreads();
  if (t == 0){
    unsigned rem = n; int c;
    if (top){ for (c = 255; c >= 0; c--){ if (csum[c] >= rem) break; rem -= csum[c]; } }
    else    { for (c = 0; c < 256; c++){ if (csum[c] >= rem) break; rem -= csum[c]; } }
    int b;
    if (top){ for (b = c*16+15; b > c*16; b--){ if (h[b] >= rem) break; rem -= h[b]; } }
    else    { for (b = c*16; b < c*16+15; b++){ if (h[b] >= rem) break; rem -= h[b]; } }
    sb = (unsigned)b; sr = rem;
  }
  __syncthreads();
  *out_bin = sb; *out_rem = sr;
  __syncthreads();
}

__global__ void k_fin1v(const unsigned* __restrict__ h1a, const unsigned* __restrict__ h1b,
                        unsigned* __restrict__ st, int round){
  unsigned nA, nB; bool topA, topB; int bA, bB;
  if (round == 0){
    nA = (unsigned)(0.2f * (float)st[0]);  // trunc, f32 mult like jnp
    topA = true;  bA = 8;
    nB = 1677721u; topB = false; bB = 16;
  } else {
    nA = 5000u; nB = 5000u; topA = topB = true; bA = 24; bB = 32;
  }
  unsigned bin, rem;
  block_select4096(h1a, nA, topA, &bin, &rem);
  if (threadIdx.x==0){ st[bA+0]=bin; st[bA+1]=rem; }
  __syncthreads();
  block_select4096(h1b, nB, topB, &bin, &rem);
  if (threadIdx.x==0){ st[bB+0]=bin; st[bB+1]=rem; }
}

// --------- collect tie-bucket elements: (full okey, idx), ~4K/side --------
__global__ void k_collect_cand(const float4* __restrict__ cam4, const int4* __restrict__ roi4,
                               const unsigned* __restrict__ st,
                               unsigned long long* __restrict__ colA,
                               unsigned long long* __restrict__ colB,
                               unsigned* __restrict__ ccnt){
  unsigned selA = st[8], selB = st[16];
  unsigned base = blockIdx.x * 8192u;
  for (int j = 0; j < 32; j++){
    unsigned u = base + threadIdx.x + (unsigned)j*256u;
    float4 c = cam4[u]; int4 r = roi4[u];
#define CC(cc, rr, kk) { unsigned i = 4u*u + (kk); \
    float vbg = (cc) + 1e-8f; \
    float vfg = (rr) ? vbg : 1e-8f; \
    if (vbin(vfg) == selA){ unsigned p = wave_reserve(&ccnt[0]); \
      if (p < COL_CAP) colA[p] = ((unsigned long long)okey(vfg) << 32) | i; } \
    if (vbin(vbg) == selB){ unsigned p = wave_reserve(&ccnt[1]); \
      if (p < COL_CAP) colB[p] = ((unsigned long long)okey(vbg) << 32) | i; } }
    CC(c.x, r.x, 0u) CC(c.y, r.y, 1u) CC(c.z, r.z, 2u) CC(c.w, r.w, 3u)
#undef CC
  }
}

// ------ exact: 4-round byte radix over full okeys + stable idx cutoff -----
__global__ void k_fin3(const unsigned long long* __restrict__ colA,
                       const unsigned long long* __restrict__ colB,
                       const unsigned* __restrict__ ccnt, unsigned* __restrict__ st,
                       int baseA, int baseB, int topA, int topB){
  __shared__ unsigned h[256];
  __shared__ unsigned eq[1024];
  __shared__ unsigned eqn, s_pref, s_rem;
  for (int side = 0; side < 2; side++){
    const unsigned long long* col = side ? colB : colA;
    int base = side ? baseB : baseA;
    bool top = side ? (topB!=0) : (topA!=0);
    unsigned m = ccnt[side]; if (m > COL_CAP) m = COL_CAP;
    if (threadIdx.x == 0){ s_pref = 0u; s_rem = st[base+1]; }
    __syncthreads();
    for (int r = 0; r < 4; r++){
      h[threadIdx.x] = 0u;            // 256 threads, 256 bins
      __syncthreads();
      unsigned pref = s_pref;
      for (unsigned e = threadIdx.x; e < m; e += 256u){
        unsigned k = (unsigned)(col[e] >> 32);
        bool act = (r == 0) || ((k >> (32 - 8*r)) == pref);
        if (act) atomicAdd(&h[(k >> (24 - 8*r)) & 0xFFu], 1u);
      }
      __syncthreads();
      if (threadIdx.x == 0){
        unsigned rem = s_rem; int b;
        if (top){ for (b = 255; b > 0; b--){ if (h[b] >= rem) break; rem -= h[b]; } }
        else    { for (b = 0; b < 255; b++){ if (h[b] >= rem) break; rem -= h[b]; } }
        s_pref = (s_pref << 8) | (unsigned)b; s_rem = rem;
      }
      __syncthreads();
    }
    unsigned T = s_pref, remF = s_rem;
    if (threadIdx.x == 0) eqn = 0u;
    __syncthreads();
    for (unsigned e = threadIdx.x; e < m; e += 256u){
      unsigned long long v = col[e];
      if ((unsigned)(v >> 32) == T){
        unsigned p = atomicAdd(&eqn, 1u);
        if (p < 1024u) eq[p] = (unsigned)v;
      }
    }
    __syncthreads();
    unsigned kq = eqn < 1024u ? eqn : 1024u;
    for (unsigned t = threadIdx.x; t < kq; t += 256u){
      unsigned idx = eq[t], rank = 0u;
      for (unsigned j = 0; j < kq; j++) if (eq[j] < idx) rank++;
      if (rank == remF - 1u){ st[base+4] = T; st[base+5] = idx; }
    }
    __syncthreads();
  }
}

// --------- candidacy map -> compact (prob,idx) lists (2-pass, L2-hot) -----
__global__ void k_cand_map(const float4* __restrict__ cam4, const int4* __restrict__ roi4,
                           unsigned* __restrict__ st,
                           unsigned long long* __restrict__ LA,
                           unsigned long long* __restrict__ LB){
  unsigned Ta = st[12], ca = st[13];
  unsigned Tb = st[20], cb = st[21];
  const unsigned OKEPS = okey(1e-8f);
  unsigned base = blockIdx.x * 8192u;
  unsigned hA = 0u, hB = 0u;
  for (int j = 0; j < 32; j++){
    unsigned u = base + threadIdx.x + (unsigned)j*256u;
    float4 c = cam4[u]; int4 r = roi4[u];
#define CM(cc, rr, kk) { unsigned i = 4u*u + (kk); \
    unsigned okb = okey((cc) + 1e-8f); \
    unsigned okf = (rr) ? okb : OKEPS; \
    if (okf > Ta || (okf == Ta && i <= ca)) hA++; \
    if (okb < Tb || (okb == Tb && i <= cb)) hB++; }
    CM(c.x, r.x, 0u) CM(c.y, r.y, 1u) CM(c.z, r.z, 2u) CM(c.w, r.w, 3u)
#undef CM
  }
  unsigned offA, offB, totA, totB;
  block_scan2(hA, hB, &offA, &offB, &totA, &totB);
  __shared__ unsigned bA_s, bB_s;
  if (threadIdx.x == 0){ bA_s = atomicAdd(&st[48], totA); bB_s = atomicAdd(&st[49], totB); }
  __syncthreads();
  unsigned pA = bA_s + offA, pB = bB_s + offB;
  for (int j = 0; j < 32; j++){
    unsigned u = base + threadIdx.x + (unsigned)j*256u;
    float4 c = cam4[u]; int4 r = roi4[u];
#define CW(cc, rr, kk) { unsigned i = 4u*u + (kk); \
    float vbg = (cc) + 1e-8f; \
    unsigned okb = okey(vbg); \
    unsigned okf = (rr) ? okb : OKEPS; \
    if (okf > Ta || (okf == Ta && i <= ca)){ \
      float prob = (rr) ? vbg : 1e-8f; \
      if (pA < LIST_CAP) LA[pA] = ((unsigned long long)__float_as_uint(prob) << 32) | i; pA++; } \
    if (okb < Tb || (okb == Tb && i <= cb)){ \
      float pb2 = fmaxf(1.0f - vbg, 0.0f) + 1e-8f; \
      if (pB < LIST_CAP) LB[pB] = ((unsigned long long)__float_as_uint(pb2) << 32) | i; pB++; } }
    CW(c.x, r.x, 0u) CW(c.y, r.y, 1u) CW(c.z, r.z, 2u) CW(c.w, r.w, 3u)
#undef CW
  }
}

// --------- dense gumbel over lists + score value-hist ---------------------
__device__ __forceinline__ float gumbel_score(uint32_t kk0, uint32_t kk1, uint32_t i, float prob){
  uint32_t y0, y1; threefry2x32(kk0, kk1, 0u, i, y0, y1);
  uint32_t bits = y0 ^ y1;                       // partitionable 32-bit fold
  float f = __uint_as_float((bits >> 9) | 0x3F800000u) - 1.0f;
  float u = fmaxf(1e-12f, f + 1e-12f);
  float l1 = (float)log((double)u);              // jnp.log(u)       (f32-rounded)
  float l2 = (float)log((double)(-l1));          // jnp.log(-log(u)) (f32-rounded)
  float lp = (float)log((double)prob);           // jnp.log(probs)   (f32-rounded)
  return lp - l2;
}

__global__ void k_gumbel(unsigned long long* __restrict__ LA,
                         unsigned long long* __restrict__ LB,
                         const unsigned* __restrict__ st,
                         unsigned* __restrict__ h1a, unsigned* __restrict__ h1b,
                         uint32_t kf0, uint32_t kf1, uint32_t kb0, uint32_t kb1){
  __shared__ unsigned la[4096], lb[4096];
  for (int j = threadIdx.x; j < 4096; j += 256){ la[j] = 0u; lb[j] = 0u; }
  __syncthreads();
  unsigned mA = st[48] < LIST_CAP ? st[48] : LIST_CAP;
  unsigned mB = st[49] < LIST_CAP ? st[49] : LIST_CAP;
  unsigned tid = blockIdx.x*256u + threadIdx.x;
  unsigned stride = gridDim.x*256u;
  for (unsigned e = tid; e < mA; e += stride){
    unsigned long long v = LA[e];
    unsigned i = (unsigned)v;
    float prob = __uint_as_float((unsigned)(v >> 32));
    float s = gumbel_score(kf0, kf1, i, prob);
    LA[e] = ((unsigned long long)okey(s) << 32) | i;
    atomicAdd(&la[sbin(s)], 1u);
  }
  for (unsigned e = tid; e < mB; e += stride){
    unsigned long long v = LB[e];
    unsigned i = (unsigned)v;
    float prob = __uint_as_float((unsigned)(v >> 32));
    float s = gumbel_score(kb0, kb1, i, prob);
    LB[e] = ((unsigned long long)okey(s) << 32) | i;
    atomicAdd(&lb[sbin(s)], 1u);
  }
  __syncthreads();
  for (int j = threadIdx.x; j < 4096; j += 256){
    unsigned va = la[j], vb = lb[j];
    if (va) atomicAdd(&h1a[j], va);
    if (vb) atomicAdd(&h1b[j], vb);
  }
}

// --------- collect score tie-bucket (~25/side) ----------------------------
__global__ void k_collect_s(const unsigned long long* __restrict__ LA,
                            const unsigned long long* __restrict__ LB,
                            const unsigned* __restrict__ st,
                            unsigned long long* __restrict__ colA,
                            unsigned long long* __restrict__ colB,
                            unsigned* __restrict__ ccnt){
  unsigned selA = st[24], selB = st[32];
  unsigned mA = st[48] < LIST_CAP ? st[48] : LIST_CAP;
  unsigned mB = st[49] < LIST_CAP ? st[49] : LIST_CAP;
  unsigned tid = blockIdx.x*256u + threadIdx.x;
  unsigned stride = gridDim.x*256u;
  for (unsigned e = tid; e < mA; e += stride){
    unsigned long long v = LA[e];
    unsigned k = (unsigned)(v >> 32);
    if (sbin(inv_okey(k)) == selA){
      unsigned p = wave_reserve(&ccnt[0]);
      if (p < COL_CAP) colA[p] = v;
    }
  }
  for (unsigned e = tid; e < mB; e += stride){
    unsigned long long v = LB[e];
    unsigned k = (unsigned)(v >> 32);
    if (sbin(inv_okey(k)) == selB){
      unsigned p = wave_reserve(&ccnt[1]);
      if (p < COL_CAP) colB[p] = v;
    }
  }
}

// --------- extract the exact 5000+5000 winner indices ---------------------
__global__ void k_winners(const unsigned long long* __restrict__ LA,
                          const unsigned long long* __restrict__ LB,
                          unsigned* __restrict__ st,
                          unsigned* __restrict__ winA, unsigned* __restrict__ winB){
  unsigned Ta = st[28], ca = st[29];
  unsigned Tb = st[36], cb = st[37];
  unsigned mA = st[48] < LIST_CAP ? st[48] : LIST_CAP;
  unsigned mB = st[49] < LIST_CAP ? st[49] : LIST_CAP;
  unsigned tid = blockIdx.x*256u + threadIdx.x;
  unsigned stride = gridDim.x*256u;
  for (unsigned e = tid; e < mA; e += stride){
    unsigned long long v = LA[e];
    unsigned k = (unsigned)(v >> 32), i = (unsigned)v;
    if (k > Ta || (k == Ta && i <= ca)){
      unsigned p = wave_reserve(&st[50]);
      if (p < WIN_CAP) winA[p] = i;
    }
  }
  for (unsigned e = tid; e < mB; e += stride){
    unsigned long long v = LB[e];
    unsigned k = (unsigned)(v >> 32), i = (unsigned)v;
    if (k > Tb || (k == Tb && i <= cb)){
      unsigned p = wave_reserve(&st[51]);
      if (p < WIN_CAP) winB[p] = i;
    }
  }
}

__global__ void k_scatter(float* __restrict__ out,
                          const unsigned* __restrict__ winA, const unsigned* __restrict__ winB,
                          const unsigned* __restrict__ st){
  unsigned t = blockIdx.x*256u + threadIdx.x;
  unsigned nA = st[50] < WIN_CAP ? st[50] : WIN_CAP;
  unsigned nB = st[51] < WIN_CAP ? st[51] : WIN_CAP;
  if (t < nA) out[winA[t]] = 1.0f;
  if (t < nB) out[HW + winB[t]] = 1.0f;
}

extern "C" void kernel_launch(void* const* d_in, const int* in_sizes, int n_in,
                              void* d_out, int out_size, void* d_ws, size_t ws_size,
                              hipStream_t stream) {
  (void)in_sizes; (void)n_in; (void)out_size; (void)ws_size;
  const float4* cam4 = (const float4*)d_in[0];
  const int4*   roi4 = (const int4*)d_in[1];
  float* out = (float*)d_out;

  // ws layout: h1a[4096] @0 | h1b[4096] @16384 | ccnt[16] @32768 | st[64] @32832
  //            winA[8192] @33280 | winB[8192] @66048   (~98 KB total)
  uint8_t* w = (uint8_t*)d_ws;
  unsigned* h1a  = (unsigned*)w;
  unsigned* h1b  = (unsigned*)(w + 16384);
  unsigned* ccnt = (unsigned*)(w + 32768);
  unsigned* st   = (unsigned*)(w + 32832);
  unsigned* winA = (unsigned*)(w + 33280);
  unsigned* winB = (unsigned*)(w + 66048);

  // candidate lists + tie-bucket collections live in d_out (128 MB scratch
  // until the final memset+scatter)
  unsigned long long* LA   = (unsigned long long*)d_out;                                 // [0,32M)
  unsigned long long* LB   = (unsigned long long*)((uint8_t*)d_out + ((size_t)32<<20));  // [32M,64M)
  unsigned long long* colA = (unsigned long long*)((uint8_t*)d_out + ((size_t)64<<20));  // 512 KB
  unsigned long long* colB = colA + COL_CAP;                                             // 512 KB

  // JAX: key(42) -> split -> k_fg, k_bg
  uint32_t kf0,kf1,kb0,kb1;
  threefry2x32(0u, 42u, 0u, 0u, kf0, kf1);
  threefry2x32(0u, 42u, 0u, 1u, kb0, kb1);

  // ---- round 0: candidate thresholds (value-binned order statistics) ----
  (void)hipMemsetAsync(w, 0, 33088, stream);      // h1a,h1b,ccnt,st
  k_hist_val<<<512, 256, 0, stream>>>(cam4, roi4, h1a, h1b, st);
  k_fin1v<<<1, 256, 0, stream>>>(h1a, h1b, st, 0);
  k_collect_cand<<<512, 256, 0, stream>>>(cam4, roi4, st, colA, colB, ccnt);
  k_fin3<<<1, 256, 0, stream>>>(colA, colB, ccnt, st, 8, 16, 1, 0);

  // ---- round 1: gumbel scores on candidates + top-5000 ----
  (void)hipMemsetAsync(w, 0, 32832, stream);      // h1a,h1b,ccnt (st preserved)
  k_cand_map<<<512, 256, 0, stream>>>(cam4, roi4, st, LA, LB);
  k_gumbel<<<512, 256, 0, stream>>>(LA, LB, st, h1a, h1b, kf0, kf1, kb0, kb1);
  k_fin1v<<<1, 256, 0, stream>>>(h1a, h1b, st, 1);
  k_collect_s<<<512, 256, 0, stream>>>(LA, LB, st, colA, colB, ccnt);
  k_fin3<<<1, 256, 0, stream>>>(colA, colB, ccnt, st, 24, 32, 1, 1);
  k_winners<<<512, 256, 0, stream>>>(LA, LB, st, winA, winB);

  // ---- final: zero masks + scatter winners ----
  (void)hipMemsetAsync(d_out, 0, (size_t)2*HW*4, stream);
  k_scatter<<<32, 256, 0, stream>>>(out, winA, winB, st);
}

// Round 6
// 587.707 us; speedup vs baseline: 1.2068x; 1.2068x over previous
//
#include <hip/hip_runtime.h>
#include <math.h>
#include <stdint.h>

#define HW 16777216u
#define COL_CAP  65536u              // tie-bucket collection cap, per side
#define LIST_CAP (4u*1024u*1024u)    // candidate list cap, per side
#define WIN_CAP  8192u

// ---------------- threefry2x32 (JAX-compatible, 20 rounds) ----------------
__host__ __device__ inline uint32_t tf_rotl(uint32_t x, int n){ return (x<<n)|(x>>(32-n)); }

__host__ __device__ inline void threefry2x32(uint32_t k0, uint32_t k1, uint32_t x0, uint32_t x1,
                                             uint32_t &o0, uint32_t &o1){
  uint32_t ks2 = k0 ^ k1 ^ 0x1BD11BDAu;
  x0 += k0; x1 += k1;
#define TF_R4(a,b,c,d) \
  x0 += x1; x1 = tf_rotl(x1,(a)); x1 ^= x0; \
  x0 += x1; x1 = tf_rotl(x1,(b)); x1 ^= x0; \
  x0 += x1; x1 = tf_rotl(x1,(c)); x1 ^= x0; \
  x0 += x1; x1 = tf_rotl(x1,(d)); x1 ^= x0;
  TF_R4(13,15,26,6)  x0 += k1;  x1 += ks2 + 1u;
  TF_R4(17,29,16,24) x0 += ks2; x1 += k0  + 2u;
  TF_R4(13,15,26,6)  x0 += k0;  x1 += k1  + 3u;
  TF_R4(17,29,16,24) x0 += k1;  x1 += ks2 + 4u;
  TF_R4(13,15,26,6)  x0 += ks2; x1 += k0  + 5u;
#undef TF_R4
  o0 = x0; o1 = x1;
}

// order-preserving uint mapping for floats (ascending)
__device__ __forceinline__ uint32_t okey(float f){
  uint32_t b = __float_as_uint(f);
  return (b & 0x80000000u) ? ~b : (b | 0x80000000u);
}
__device__ __forceinline__ float inv_okey(uint32_t k){
  uint32_t b = (k & 0x80000000u) ? (k & 0x7FFFFFFFu) : ~k;
  return __uint_as_float(b);
}

// value-domain bins (monotone in okey for v>=0). cam uniform [0,1] -> ~4096/bin.
__device__ __forceinline__ unsigned vbin(float v){
  unsigned b = (unsigned)(v * 4096.0f);
  return b > 4095u ? 4095u : b;
}
// score-domain bins: scores lie in ~[-3.6, 16). monotone affine map.
__device__ __forceinline__ unsigned sbin(float s){
  float t = (s + 4.0f) * 204.8f;
  int b = (int)t;
  b = b < 0 ? 0 : (b > 4095 ? 4095 : b);
  return (unsigned)b;
}

// wave-aggregated reserve on an LDS counter: one LDS atomic per wave.
// (rounds 2/5 post-mortem: contended GLOBAL atomic-with-return is ~11ns
//  serialized — only ever issue it once per block.)
__device__ __forceinline__ unsigned wave_reserve_lds(unsigned* cnt){
  unsigned long long m = __ballot(1);
  unsigned lane = threadIdx.x & 63u;
  unsigned leader = (unsigned)__ffsll((unsigned long long)m) - 1u;
  unsigned prefix = (unsigned)__popcll(m & ((1ull << lane) - 1ull));
  unsigned base = 0u;
  if (lane == leader) base = atomicAdd(cnt, (unsigned)__popcll(m));
  base = __shfl(base, (int)leader, 64);
  return base + prefix;
}

// st layout (u32): [0]=sum(roi)
//  fg_cand base 8 / bg_cand 16 / fg_score 24 / bg_score 32:
//    +0 bin, +1 rem, +4 T(okey), +5 cut_idx
//  [48],[49] list counts; [50],[51] winner counts
// ccnt: [0],[1] collection counts (reused per round)

// --------- pass 1: packed value-hist (fg hi16, bg lo16) + roi sum ---------
__global__ void k_hist_val(const float4* __restrict__ cam4, const int4* __restrict__ roi4,
                           unsigned* __restrict__ h1a, unsigned* __restrict__ h1b,
                           unsigned* __restrict__ st){
  __shared__ unsigned hp[4096];
  __shared__ unsigned ssum;
  for (int j = threadIdx.x; j < 4096; j += 256) hp[j] = 0u;
  if (threadIdx.x == 0) ssum = 0u;
  __syncthreads();
  unsigned base = blockIdx.x * 8192u;   // float4 units; block covers 32768 elems
  unsigned rs = 0u;
  for (int j = 0; j < 32; j++){
    unsigned u = base + threadIdx.x + (unsigned)j*256u;
    float4 c = cam4[u]; int4 r = roi4[u];
#define HV(cc, rr) { unsigned b = vbin((cc) + 1e-8f); \
    atomicAdd(&hp[b], (rr) ? 0x10001u : 1u); rs += (unsigned)(rr); }
    HV(c.x, r.x) HV(c.y, r.y) HV(c.z, r.z) HV(c.w, r.w)
#undef HV
  }
  atomicAdd(&ssum, rs);
  __syncthreads();
  for (int j = threadIdx.x; j < 4096; j += 256){
    unsigned p = hp[j];
    if (p){
      unsigned fa = p >> 16, fb = p & 0xFFFFu;
      if (fa) atomicAdd(&h1a[j], fa);
      if (fb) atomicAdd(&h1b[j], fb);
    }
  }
  if (threadIdx.x == 0) atomicAdd(&st[0], ssum);
}

// --------------- block-cooperative select over 4096-bin hist --------------
__device__ void block_select4096(const unsigned* __restrict__ h, unsigned n, bool top,
                                 unsigned* out_bin, unsigned* out_rem){
  __shared__ unsigned csum[256];
  __shared__ unsigned sb, sr;
  unsigned t = threadIdx.x;
  unsigned s = 0u;
  #pragma unroll
  for (int j = 0; j < 16; j++) s += h[t*16 + j];
  csum[t] = s;
  __syncthreads();
  if (t == 0){
    unsigned rem = n; int c;
    if (top){ for (c = 255; c >= 0; c--){ if (csum[c] >= rem) break; rem -= csum[c]; } }
    else    { for (c = 0; c < 256; c++){ if (csum[c] >= rem) break; rem -= csum[c]; } }
    int b;
    if (top){ for (b = c*16+15; b > c*16; b--){ if (h[b] >= rem) break; rem -= h[b]; } }
    else    { for (b = c*16; b < c*16+15; b++){ if (h[b] >= rem) break; rem -= h[b]; } }
    sb = (unsigned)b; sr = rem;
  }
  __syncthreads();
  *out_bin = sb; *out_rem = sr;
  __syncthreads();
}

__global__ void k_fin1v(const unsigned* __restrict__ h1a, const unsigned* __restrict__ h1b,
                        unsigned* __restrict__ st, int round){
  unsigned nA, nB; bool topA, topB; int bA, bB;
  if (round == 0){
    nA = (unsigned)(0.2f * (float)st[0]);  // trunc, f32 mult like jnp
    topA = true;  bA = 8;
    nB = 1677721u; topB = false; bB = 16;
  } else {
    nA = 5000u; nB = 5000u; topA = topB = true; bA = 24; bB = 32;
  }
  unsigned bin, rem;
  block_select4096(h1a, nA, topA, &bin, &rem);
  if (threadIdx.x==0){ st[bA+0]=bin; st[bA+1]=rem; }
  __syncthreads();
  block_select4096(h1b, nB, topB, &bin, &rem);
  if (threadIdx.x==0){ st[bB+0]=bin; st[bB+1]=rem; }
}

// --------- collect tie-bucket elements (LDS-buffered block append) --------
__global__ void k_collect_cand(const float4* __restrict__ cam4, const int4* __restrict__ roi4,
                               const unsigned* __restrict__ st,
                               unsigned long long* __restrict__ colA,
                               unsigned long long* __restrict__ colB,
                               unsigned* __restrict__ ccnt){
  __shared__ unsigned long long bufA[1024], bufB[1024];
  __shared__ unsigned nA_s, nB_s, bA_s, bB_s;
  if (threadIdx.x == 0){ nA_s = 0u; nB_s = 0u; }
  __syncthreads();
  unsigned selA = st[8], selB = st[16];
  unsigned base = blockIdx.x * 8192u;
  for (int j = 0; j < 32; j++){
    unsigned u = base + threadIdx.x + (unsigned)j*256u;
    float4 c = cam4[u]; int4 r = roi4[u];
#define CC(cc, rr, kk) { unsigned i = 4u*u + (kk); \
    float vbg = (cc) + 1e-8f; \
    float vfg = (rr) ? vbg : 1e-8f; \
    if (vbin(vfg) == selA){ unsigned p = wave_reserve_lds(&nA_s); \
      if (p < 1024u) bufA[p] = ((unsigned long long)okey(vfg) << 32) | i; } \
    if (vbin(vbg) == selB){ unsigned p = wave_reserve_lds(&nB_s); \
      if (p < 1024u) bufB[p] = ((unsigned long long)okey(vbg) << 32) | i; } }
    CC(c.x, r.x, 0u) CC(c.y, r.y, 1u) CC(c.z, r.z, 2u) CC(c.w, r.w, 3u)
#undef CC
  }
  __syncthreads();
  if (threadIdx.x == 0){
    unsigned tA = nA_s < 1024u ? nA_s : 1024u;
    unsigned tB = nB_s < 1024u ? nB_s : 1024u;
    nA_s = tA; nB_s = tB;
    bA_s = atomicAdd(&ccnt[0], tA); bB_s = atomicAdd(&ccnt[1], tB);
  }
  __syncthreads();
  for (unsigned t = threadIdx.x; t < nA_s; t += 256u)
    if (bA_s + t < COL_CAP) colA[bA_s + t] = bufA[t];
  for (unsigned t = threadIdx.x; t < nB_s; t += 256u)
    if (bB_s + t < COL_CAP) colB[bB_s + t] = bufB[t];
}

// ------ exact: 4-round byte radix over full okeys + stable idx cutoff -----
__global__ void k_fin3(const unsigned long long* __restrict__ colA,
                       const unsigned long long* __restrict__ colB,
                       const unsigned* __restrict__ ccnt, unsigned* __restrict__ st,
                       int baseA, int baseB, int topA, int topB){
  __shared__ unsigned h[256];
  __shared__ unsigned eq[1024];
  __shared__ unsigned eqn, s_pref, s_rem;
  for (int side = 0; side < 2; side++){
    const unsigned long long* col = side ? colB : colA;
    int base = side ? baseB : baseA;
    bool top = side ? (topB!=0) : (topA!=0);
    unsigned m = ccnt[side]; if (m > COL_CAP) m = COL_CAP;
    unsigned n = st[base+1];
    if (threadIdx.x == 0){ s_pref = 0u; s_rem = n; }
    __syncthreads();
    for (int r = 0; r < 4; r++){
      h[threadIdx.x] = 0u;
      __syncthreads();
      unsigned pref = s_pref;
      for (unsigned e = threadIdx.x; e < m; e += 256u){
        unsigned k = (unsigned)(col[e] >> 32);
        bool act = (r == 0) || ((k >> (32 - 8*r)) == pref);
        if (act) atomicAdd(&h[(k >> (24 - 8*r)) & 0xFFu], 1u);
      }
      __syncthreads();
      if (threadIdx.x == 0){
        unsigned rem = s_rem; int b;
        if (top){ for (b = 255; b > 0; b--){ if (h[b] >= rem) break; rem -= h[b]; } }
        else    { for (b = 0; b < 255; b++){ if (h[b] >= rem) break; rem -= h[b]; } }
        s_pref = (s_pref << 8) | (unsigned)b; s_rem = rem;
      }
      __syncthreads();
    }
    unsigned T = s_pref, remF = s_rem;
    if (threadIdx.x == 0) eqn = 0u;
    __syncthreads();
    for (unsigned e = threadIdx.x; e < m; e += 256u){
      unsigned long long v = col[e];
      if ((unsigned)(v >> 32) == T){
        unsigned p = atomicAdd(&eqn, 1u);
        if (p < 1024u) eq[p] = (unsigned)v;
      }
    }
    __syncthreads();
    unsigned kq = eqn < 1024u ? eqn : 1024u;
    for (unsigned t = threadIdx.x; t < kq; t += 256u){
      unsigned idx = eq[t], rank = 0u;
      for (unsigned j = 0; j < kq; j++) if (eq[j] < idx) rank++;
      if (rank == remF - 1u){ st[base+4] = T; st[base+5] = idx; }
    }
    __syncthreads();
  }
}

// --------- fused: candidacy map + dense gumbel + score hist (1 pass) ------
__device__ __forceinline__ float gumbel_score(uint32_t kk0, uint32_t kk1, uint32_t i, float prob){
  uint32_t y0, y1; threefry2x32(kk0, kk1, 0u, i, y0, y1);
  uint32_t bits = y0 ^ y1;                       // partitionable 32-bit fold
  float f = __uint_as_float((bits >> 9) | 0x3F800000u) - 1.0f;
  float u = fmaxf(1e-12f, f + 1e-12f);
  float l1 = (float)log((double)u);              // jnp.log(u)       (f32-rounded)
  float l2 = (float)log((double)(-l1));          // jnp.log(-log(u)) (f32-rounded)
  float lp = (float)log((double)prob);           // jnp.log(probs)   (f32-rounded)
  return lp - l2;
}

__global__ __launch_bounds__(256) void k_map_gumbel(
    const float4* __restrict__ cam4, const int4* __restrict__ roi4,
    unsigned* __restrict__ st,
    unsigned long long* __restrict__ LA, unsigned long long* __restrict__ LB,
    unsigned* __restrict__ h1a, unsigned* __restrict__ h1b,
    uint32_t kf0, uint32_t kf1, uint32_t kb0, uint32_t kb1){
  __shared__ unsigned long long bufA[1536], bufB[1536];   // 24 KB (prob,idx)
  __shared__ unsigned la[4096], lb[4096];                 // 32 KB score hists
  __shared__ unsigned nA_s, nB_s, bA_s, bB_s;
  for (int j = threadIdx.x; j < 4096; j += 256){ la[j] = 0u; lb[j] = 0u; }
  unsigned Ta = st[12], ca = st[13];
  unsigned Tb = st[20], cb = st[21];
  const unsigned OKEPS = okey(1e-8f);
  unsigned base = blockIdx.x * 8192u;    // block covers 8192 float4 = 32768 elems
  for (int chunk = 0; chunk < 4; chunk++){
    if (threadIdx.x == 0){ nA_s = 0u; nB_s = 0u; }
    __syncthreads();
    // phase 1: compact candidates of this 8192-elem chunk into LDS
    for (int j = 0; j < 8; j++){
      unsigned u = base + (unsigned)chunk*2048u + threadIdx.x + (unsigned)j*256u;
      float4 c = cam4[u]; int4 r = roi4[u];
#define MG(cc, rr, kk) { unsigned i = 4u*u + (kk); \
    float vbg = (cc) + 1e-8f; \
    unsigned okb = okey(vbg); \
    unsigned okf = (rr) ? okb : OKEPS; \
    if (okf > Ta || (okf == Ta && i <= ca)){ \
      float prob = (rr) ? vbg : 1e-8f; \
      unsigned p = wave_reserve_lds(&nA_s); \
      if (p < 1536u) bufA[p] = ((unsigned long long)__float_as_uint(prob) << 32) | i; } \
    if (okb < Tb || (okb == Tb && i <= cb)){ \
      float pb2 = fmaxf(1.0f - vbg, 0.0f) + 1e-8f; \
      unsigned p = wave_reserve_lds(&nB_s); \
      if (p < 1536u) bufB[p] = ((unsigned long long)__float_as_uint(pb2) << 32) | i; } }
      MG(c.x, r.x, 0u) MG(c.y, r.y, 1u) MG(c.z, r.z, 2u) MG(c.w, r.w, 3u)
#undef MG
    }
    __syncthreads();
    if (threadIdx.x == 0){
      unsigned tA = nA_s < 1536u ? nA_s : 1536u;
      unsigned tB = nB_s < 1536u ? nB_s : 1536u;
      nA_s = tA; nB_s = tB;
      bA_s = atomicAdd(&st[48], tA); bB_s = atomicAdd(&st[49], tB);
    }
    __syncthreads();
    // phase 2: dense gumbel over compacted candidates (full lane occupancy)
    for (unsigned e = threadIdx.x; e < nA_s; e += 256u){
      unsigned long long v = bufA[e];
      unsigned i = (unsigned)v;
      float prob = __uint_as_float((unsigned)(v >> 32));
      float s = gumbel_score(kf0, kf1, i, prob);
      unsigned p = bA_s + e;
      if (p < LIST_CAP) LA[p] = ((unsigned long long)okey(s) << 32) | i;
      atomicAdd(&la[sbin(s)], 1u);
    }
    for (unsigned e = threadIdx.x; e < nB_s; e += 256u){
      unsigned long long v = bufB[e];
      unsigned i = (unsigned)v;
      float prob = __uint_as_float((unsigned)(v >> 32));
      float s = gumbel_score(kb0, kb1, i, prob);
      unsigned p = bB_s + e;
      if (p < LIST_CAP) LB[p] = ((unsigned long long)okey(s) << 32) | i;
      atomicAdd(&lb[sbin(s)], 1u);
    }
    __syncthreads();
  }
  for (int j = threadIdx.x; j < 4096; j += 256){
    unsigned va = la[j], vb = lb[j];
    if (va) atomicAdd(&h1a[j], va);
    if (vb) atomicAdd(&h1b[j], vb);
  }
}

// --------- collect score tie-bucket (LDS-buffered) ------------------------
__global__ void k_collect_s(const unsigned long long* __restrict__ LA,
                            const unsigned long long* __restrict__ LB,
                            const unsigned* __restrict__ st,
                            unsigned long long* __restrict__ colA,
                            unsigned long long* __restrict__ colB,
                            unsigned* __restrict__ ccnt){
  __shared__ unsigned long long bufA[512], bufB[512];
  __shared__ unsigned nA_s, nB_s, bA_s, bB_s;
  if (threadIdx.x == 0){ nA_s = 0u; nB_s = 0u; }
  __syncthreads();
  unsigned selA = st[24], selB = st[32];
  unsigned mA = st[48] < LIST_CAP ? st[48] : LIST_CAP;
  unsigned mB = st[49] < LIST_CAP ? st[49] : LIST_CAP;
  unsigned tid = blockIdx.x*256u + threadIdx.x;
  unsigned stride = gridDim.x*256u;
  for (unsigned e = tid; e < mA; e += stride){
    unsigned long long v = LA[e];
    if (sbin(inv_okey((unsigned)(v >> 32))) == selA){
      unsigned p = wave_reserve_lds(&nA_s);
      if (p < 512u) bufA[p] = v;
    }
  }
  for (unsigned e = tid; e < mB; e += stride){
    unsigned long long v = LB[e];
    if (sbin(inv_okey((unsigned)(v >> 32))) == selB){
      unsigned p = wave_reserve_lds(&nB_s);
      if (p < 512u) bufB[p] = v;
    }
  }
  __syncthreads();
  if (threadIdx.x == 0){
    unsigned tA = nA_s < 512u ? nA_s : 512u;
    unsigned tB = nB_s < 512u ? nB_s : 512u;
    nA_s = tA; nB_s = tB;
    bA_s = atomicAdd(&ccnt[0], tA); bB_s = atomicAdd(&ccnt[1], tB);
  }
  __syncthreads();
  for (unsigned t = threadIdx.x; t < nA_s; t += 256u)
    if (bA_s + t < COL_CAP) colA[bA_s + t] = bufA[t];
  for (unsigned t = threadIdx.x; t < nB_s; t += 256u)
    if (bB_s + t < COL_CAP) colB[bB_s + t] = bufB[t];
}

// --------- extract exact 5000+5000 winner indices (LDS-buffered) ----------
__global__ void k_winners(const unsigned long long* __restrict__ LA,
                          const unsigned long long* __restrict__ LB,
                          unsigned* __restrict__ st,
                          unsigned* __restrict__ winA, unsigned* __restrict__ winB){
  __shared__ unsigned bufA[1024], bufB[1024];
  __shared__ unsigned nA_s, nB_s, bA_s, bB_s;
  if (threadIdx.x == 0){ nA_s = 0u; nB_s = 0u; }
  __syncthreads();
  unsigned Ta = st[28], ca = st[29];
  unsigned Tb = st[36], cb = st[37];
  unsigned mA = st[48] < LIST_CAP ? st[48] : LIST_CAP;
  unsigned mB = st[49] < LIST_CAP ? st[49] : LIST_CAP;
  unsigned tid = blockIdx.x*256u + threadIdx.x;
  unsigned stride = gridDim.x*256u;
  for (unsigned e = tid; e < mA; e += stride){
    unsigned long long v = LA[e];
    unsigned k = (unsigned)(v >> 32), i = (unsigned)v;
    if (k > Ta || (k == Ta && i <= ca)){
      unsigned p = wave_reserve_lds(&nA_s);
      if (p < 1024u) bufA[p] = i;
    }
  }
  for (unsigned e = tid; e < mB; e += stride){
    unsigned long long v = LB[e];
    unsigned k = (unsigned)(v >> 32), i = (unsigned)v;
    if (k > Tb || (k == Tb && i <= cb)){
      unsigned p = wave_reserve_lds(&nB_s);
      if (p < 1024u) bufB[p] = i;
    }
  }
  __syncthreads();
  if (threadIdx.x == 0){
    unsigned tA = nA_s < 1024u ? nA_s : 1024u;
    unsigned tB = nB_s < 1024u ? nB_s : 1024u;
    nA_s = tA; nB_s = tB;
    bA_s = atomicAdd(&st[50], tA); bB_s = atomicAdd(&st[51], tB);
  }
  __syncthreads();
  for (unsigned t = threadIdx.x; t < nA_s; t += 256u)
    if (bA_s + t < WIN_CAP) winA[bA_s + t] = bufA[t];
  for (unsigned t = threadIdx.x; t < nB_s; t += 256u)
    if (bB_s + t < WIN_CAP) winB[bB_s + t] = bufB[t];
}

__global__ void k_scatter(float* __restrict__ out,
                          const unsigned* __restrict__ winA, const unsigned* __restrict__ winB,
                          const unsigned* __restrict__ st){
  unsigned t = blockIdx.x*256u + threadIdx.x;
  unsigned nA = st[50] < WIN_CAP ? st[50] : WIN_CAP;
  unsigned nB = st[51] < WIN_CAP ? st[51] : WIN_CAP;
  if (t < nA) out[winA[t]] = 1.0f;
  if (t < nB) out[HW + winB[t]] = 1.0f;
}

extern "C" void kernel_launch(void* const* d_in, const int* in_sizes, int n_in,
                              void* d_out, int out_size, void* d_ws, size_t ws_size,
                              hipStream_t stream) {
  (void)in_sizes; (void)n_in; (void)out_size; (void)ws_size;
  const float4* cam4 = (const float4*)d_in[0];
  const int4*   roi4 = (const int4*)d_in[1];
  float* out = (float*)d_out;

  // ws layout: h1a[4096] @0 | h1b[4096] @16384 | ccnt[16] @32768 | st[64] @32832
  //            winA[8192] @33280 | winB[8192] @66048   (~98 KB total)
  uint8_t* w = (uint8_t*)d_ws;
  unsigned* h1a  = (unsigned*)w;
  unsigned* h1b  = (unsigned*)(w + 16384);
  unsigned* ccnt = (unsigned*)(w + 32768);
  unsigned* st   = (unsigned*)(w + 32832);
  unsigned* winA = (unsigned*)(w + 33280);
  unsigned* winB = (unsigned*)(w + 66048);

  // score lists + tie-bucket collections live in d_out (128 MB scratch until
  // the final memset+scatter)
  unsigned long long* LA   = (unsigned long long*)d_out;                                 // [0,32M)
  unsigned long long* LB   = (unsigned long long*)((uint8_t*)d_out + ((size_t)32<<20));  // [32M,64M)
  unsigned long long* colA = (unsigned long long*)((uint8_t*)d_out + ((size_t)64<<20));  // 512 KB
  unsigned long long* colB = colA + COL_CAP;                                             // 512 KB

  // JAX: key(42) -> split -> k_fg, k_bg
  uint32_t kf0,kf1,kb0,kb1;
  threefry2x32(0u, 42u, 0u, 0u, kf0, kf1);
  threefry2x32(0u, 42u, 0u, 1u, kb0, kb1);

  // ---- round 0: candidate thresholds (value-binned order statistics) ----
  (void)hipMemsetAsync(w, 0, 33088, stream);      // h1a,h1b,ccnt,st
  k_hist_val<<<512, 256, 0, stream>>>(cam4, roi4, h1a, h1b, st);
  k_fin1v<<<1, 256, 0, stream>>>(h1a, h1b, st, 0);
  k_collect_cand<<<512, 256, 0, stream>>>(cam4, roi4, st, colA, colB, ccnt);
  k_fin3<<<1, 256, 0, stream>>>(colA, colB, ccnt, st, 8, 16, 1, 0);

  // ---- round 1: fused candidacy+gumbel, then top-5000 ----
  (void)hipMemsetAsync(w, 0, 32832, stream);      // h1a,h1b,ccnt (st preserved)
  k_map_gumbel<<<512, 256, 0, stream>>>(cam4, roi4, st, LA, LB, h1a, h1b, kf0, kf1, kb0, kb1);
  k_fin1v<<<1, 256, 0, stream>>>(h1a, h1b, st, 1);
  k_collect_s<<<512, 256, 0, stream>>>(LA, LB, st, colA, colB, ccnt);
  k_fin3<<<1, 256, 0, stream>>>(colA, colB, ccnt, st, 24, 32, 1, 1);
  k_winners<<<512, 256, 0, stream>>>(LA, LB, st, winA, winB);

  // ---- final: zero masks + scatter winners ----
  (void)hipMemsetAsync(d_out, 0, (size_t)2*HW*4, stream);
  k_scatter<<<32, 256, 0, stream>>>(out, winA, winB, st);
}

// Round 7
// 507.190 us; speedup vs baseline: 1.3984x; 1.1588x over previous
//
#include <hip/hip_runtime.h>
#include <math.h>
#include <stdint.h>

#define HW 16777216u
#define COL_CAP  65536u              // tie-bucket collection cap, per side
#define LIST_CAP (4u*1024u*1024u)    // candidate list cap, per side
#define WIN_CAP  8192u

// ---------------- threefry2x32 (JAX-compatible, 20 rounds) ----------------
__host__ __device__ inline uint32_t tf_rotl(uint32_t x, int n){ return (x<<n)|(x>>(32-n)); }

__host__ __device__ inline void threefry2x32(uint32_t k0, uint32_t k1, uint32_t x0, uint32_t x1,
                                             uint32_t &o0, uint32_t &o1){
  uint32_t ks2 = k0 ^ k1 ^ 0x1BD11BDAu;
  x0 += k0; x1 += k1;
#define TF_R4(a,b,c,d) \
  x0 += x1; x1 = tf_rotl(x1,(a)); x1 ^= x0; \
  x0 += x1; x1 = tf_rotl(x1,(b)); x1 ^= x0; \
  x0 += x1; x1 = tf_rotl(x1,(c)); x1 ^= x0; \
  x0 += x1; x1 = tf_rotl(x1,(d)); x1 ^= x0;
  TF_R4(13,15,26,6)  x0 += k1;  x1 += ks2 + 1u;
  TF_R4(17,29,16,24) x0 += ks2; x1 += k0  + 2u;
  TF_R4(13,15,26,6)  x0 += k0;  x1 += k1  + 3u;
  TF_R4(17,29,16,24) x0 += k1;  x1 += ks2 + 4u;
  TF_R4(13,15,26,6)  x0 += ks2; x1 += k0  + 5u;
#undef TF_R4
  o0 = x0; o1 = x1;
}

// order-preserving uint mapping for floats (ascending)
__device__ __forceinline__ uint32_t okey(float f){
  uint32_t b = __float_as_uint(f);
  return (b & 0x80000000u) ? ~b : (b | 0x80000000u);
}
__device__ __forceinline__ float inv_okey(uint32_t k){
  uint32_t b = (k & 0x80000000u) ? (k & 0x7FFFFFFFu) : ~k;
  return __uint_as_float(b);
}

// value-domain bins (monotone in okey for v>=0). cam uniform [0,1] -> ~4096/bin.
__device__ __forceinline__ unsigned vbin(float v){
  unsigned b = (unsigned)(v * 4096.0f);
  return b > 4095u ? 4095u : b;
}
// score-domain bins (1024): scores lie in ~[-22, 16.6); threshold ~5.8 -> mid-range.
__device__ __forceinline__ unsigned sbin(float s){
  float t = (s + 4.0f) * 51.2f;
  int b = (int)t;
  b = b < 0 ? 0 : (b > 1023 ? 1023 : b);
  return (unsigned)b;
}

// wave-aggregated reserve on an LDS counter: one LDS atomic per wave.
// (rounds 2/5: contended GLOBAL atomic-with-return is ~11ns serialized —
//  only ever issue it once per block.)
__device__ __forceinline__ unsigned wave_reserve_lds(unsigned* cnt){
  unsigned long long m = __ballot(1);
  unsigned lane = threadIdx.x & 63u;
  unsigned leader = (unsigned)__ffsll((unsigned long long)m) - 1u;
  unsigned prefix = (unsigned)__popcll(m & ((1ull << lane) - 1ull));
  unsigned base = 0u;
  if (lane == leader) base = atomicAdd(cnt, (unsigned)__popcll(m));
  base = __shfl(base, (int)leader, 64);
  return base + prefix;
}

// st layout (u32): [0]=sum(roi)
//  fg_cand base 8 / bg_cand 16 / fg_score 24 / bg_score 32:
//    +0 bin, +1 rem, +4 T(okey), +5 cut_idx
//  [48],[49] list counts; [50],[51] winner counts

// --------- pass 1: packed value-hist (fg hi16, bg lo16) + roi sum ---------
// 512 blocks x 1024 thr: 2 resident blocks/CU = 32 waves (100% occ).
__global__ __launch_bounds__(1024) void k_hist_val(
    const float4* __restrict__ cam4, const int4* __restrict__ roi4,
    unsigned* __restrict__ h1a, unsigned* __restrict__ h1b,
    unsigned* __restrict__ st){
  __shared__ unsigned hp[4096];
  __shared__ unsigned ssum;
  for (int j = threadIdx.x; j < 4096; j += 1024) hp[j] = 0u;
  if (threadIdx.x == 0) ssum = 0u;
  __syncthreads();
  unsigned base = blockIdx.x * 8192u;   // float4 units; block covers 32768 elems
  unsigned rs = 0u;
  for (int j = 0; j < 8; j++){
    unsigned u = base + threadIdx.x + (unsigned)j*1024u;
    float4 c = cam4[u]; int4 r = roi4[u];
#define HV(cc, rr) { unsigned b = vbin((cc) + 1e-8f); \
    atomicAdd(&hp[b], (rr) ? 0x10001u : 1u); rs += (unsigned)(rr); }
    HV(c.x, r.x) HV(c.y, r.y) HV(c.z, r.z) HV(c.w, r.w)
#undef HV
  }
  for (int o = 32; o; o >>= 1) rs += __shfl_down(rs, o, 64);
  if ((threadIdx.x & 63u) == 0u) atomicAdd(&ssum, rs);
  __syncthreads();
  for (int j = threadIdx.x; j < 4096; j += 1024){
    unsigned p = hp[j];
    if (p){
      unsigned fa = p >> 16, fb = p & 0xFFFFu;
      if (fa) atomicAdd(&h1a[j], fa);
      if (fb) atomicAdd(&h1b[j], fb);
    }
  }
  if (threadIdx.x == 0) atomicAdd(&st[0], ssum);
}

// ---- block-cooperative selects (block-size agnostic; >=256 threads) ------
__device__ void block_select4096(const unsigned* __restrict__ h, unsigned n, bool top,
                                 unsigned* out_bin, unsigned* out_rem){
  __shared__ unsigned csum[256];
  __shared__ unsigned sb, sr;
  unsigned t = threadIdx.x;
  if (t < 256u){
    unsigned s = 0u;
    #pragma unroll
    for (int j = 0; j < 16; j++) s += h[t*16 + j];
    csum[t] = s;
  }
  __syncthreads();
  if (t == 0){
    unsigned rem = n; int c;
    if (top){ for (c = 255; c >= 0; c--){ if (csum[c] >= rem) break; rem -= csum[c]; } }
    else    { for (c = 0; c < 256; c++){ if (csum[c] >= rem) break; rem -= csum[c]; } }
    int b;
    if (top){ for (b = c*16+15; b > c*16; b--){ if (h[b] >= rem) break; rem -= h[b]; } }
    else    { for (b = c*16; b < c*16+15; b++){ if (h[b] >= rem) break; rem -= h[b]; } }
    sb = (unsigned)b; sr = rem;
  }
  __syncthreads();
  *out_bin = sb; *out_rem = sr;
  __syncthreads();
}

__device__ void block_select1024(const unsigned* __restrict__ h, unsigned n, bool top,
                                 unsigned* out_bin, unsigned* out_rem){
  __shared__ unsigned csum[256];
  __shared__ unsigned sb, sr;
  unsigned t = threadIdx.x;
  if (t < 256u){
    unsigned s = 0u;
    #pragma unroll
    for (int j = 0; j < 4; j++) s += h[t*4 + j];
    csum[t] = s;
  }
  __syncthreads();
  if (t == 0){
    unsigned rem = n; int c;
    if (top){ for (c = 255; c >= 0; c--){ if (csum[c] >= rem) break; rem -= csum[c]; } }
    else    { for (c = 0; c < 256; c++){ if (csum[c] >= rem) break; rem -= csum[c]; } }
    int b;
    if (top){ for (b = c*4+3; b > c*4; b--){ if (h[b] >= rem) break; rem -= h[b]; } }
    else    { for (b = c*4; b < c*4+3; b++){ if (h[b] >= rem) break; rem -= h[b]; } }
    sb = (unsigned)b; sr = rem;
  }
  __syncthreads();
  *out_bin = sb; *out_rem = sr;
  __syncthreads();
}

// --- collect cand tie-bucket (inline fin1 recompute; LDS-buffered) --------
__global__ __launch_bounds__(1024) void k_collect_cand(
    const float4* __restrict__ cam4, const int4* __restrict__ roi4,
    const unsigned* __restrict__ h1a, const unsigned* __restrict__ h1b,
    unsigned* __restrict__ st,
    unsigned long long* __restrict__ colA, unsigned long long* __restrict__ colB,
    unsigned* __restrict__ ccnt){
  __shared__ unsigned long long bufA[512], bufB[512];
  __shared__ unsigned nA_s, nB_s, bA_s, bB_s;
  unsigned selA, remA, selB, remB;
  unsigned nA = (unsigned)(0.2f * (float)st[0]);   // trunc, f32 mult like jnp
  block_select4096(h1a, nA, true, &selA, &remA);
  block_select4096(h1b, 1677721u, false, &selB, &remB);
  if (blockIdx.x == 0 && threadIdx.x == 0){
    st[8] = selA; st[9] = remA; st[16] = selB; st[17] = remB;
  }
  if (threadIdx.x == 0){ nA_s = 0u; nB_s = 0u; }
  __syncthreads();
  unsigned base = blockIdx.x * 8192u;
  for (int j = 0; j < 8; j++){
    unsigned u = base + threadIdx.x + (unsigned)j*1024u;
    float4 c = cam4[u]; int4 r = roi4[u];
#define CC(cc, rr, kk) { unsigned i = 4u*u + (kk); \
    float vbg = (cc) + 1e-8f; \
    float vfg = (rr) ? vbg : 1e-8f; \
    if (vbin(vfg) == selA){ unsigned p = wave_reserve_lds(&nA_s); \
      if (p < 512u) bufA[p] = ((unsigned long long)okey(vfg) << 32) | i; } \
    if (vbin(vbg) == selB){ unsigned p = wave_reserve_lds(&nB_s); \
      if (p < 512u) bufB[p] = ((unsigned long long)okey(vbg) << 32) | i; } }
    CC(c.x, r.x, 0u) CC(c.y, r.y, 1u) CC(c.z, r.z, 2u) CC(c.w, r.w, 3u)
#undef CC
  }
  __syncthreads();
  if (threadIdx.x == 0){
    unsigned tA = nA_s < 512u ? nA_s : 512u;
    unsigned tB = nB_s < 512u ? nB_s : 512u;
    nA_s = tA; nB_s = tB;
    bA_s = atomicAdd(&ccnt[0], tA); bB_s = atomicAdd(&ccnt[1], tB);
  }
  __syncthreads();
  for (unsigned t = threadIdx.x; t < nA_s; t += 1024u)
    if (bA_s + t < COL_CAP) colA[bA_s + t] = bufA[t];
  for (unsigned t = threadIdx.x; t < nB_s; t += 1024u)
    if (bB_s + t < COL_CAP) colB[bB_s + t] = bufB[t];
}

// ------ exact: 4-round byte radix over full okeys + stable idx cutoff -----
__global__ void k_fin3(const unsigned long long* __restrict__ colA,
                       const unsigned long long* __restrict__ colB,
                       const unsigned* __restrict__ ccnt, unsigned* __restrict__ st,
                       int baseA, int baseB, int topA, int topB){
  __shared__ unsigned h[256];
  __shared__ unsigned eq[1024];
  __shared__ unsigned eqn, s_pref, s_rem;
  for (int side = 0; side < 2; side++){
    const unsigned long long* col = side ? colB : colA;
    int base = side ? baseB : baseA;
    bool top = side ? (topB!=0) : (topA!=0);
    unsigned m = ccnt[side]; if (m > COL_CAP) m = COL_CAP;
    unsigned n = st[base+1];
    if (threadIdx.x == 0){ s_pref = 0u; s_rem = n; }
    __syncthreads();
    for (int r = 0; r < 4; r++){
      h[threadIdx.x] = 0u;
      __syncthreads();
      unsigned pref = s_pref;
      for (unsigned e = threadIdx.x; e < m; e += 256u){
        unsigned k = (unsigned)(col[e] >> 32);
        bool act = (r == 0) || ((k >> (32 - 8*r)) == pref);
        if (act) atomicAdd(&h[(k >> (24 - 8*r)) & 0xFFu], 1u);
      }
      __syncthreads();
      if (threadIdx.x == 0){
        unsigned rem = s_rem; int b;
        if (top){ for (b = 255; b > 0; b--){ if (h[b] >= rem) break; rem -= h[b]; } }
        else    { for (b = 0; b < 255; b++){ if (h[b] >= rem) break; rem -= h[b]; } }
        s_pref = (s_pref << 8) | (unsigned)b; s_rem = rem;
      }
      __syncthreads();
    }
    unsigned T = s_pref, remF = s_rem;
    if (threadIdx.x == 0) eqn = 0u;
    __syncthreads();
    for (unsigned e = threadIdx.x; e < m; e += 256u){
      unsigned long long v = col[e];
      if ((unsigned)(v >> 32) == T){
        unsigned p = atomicAdd(&eqn, 1u);
        if (p < 1024u) eq[p] = (unsigned)v;
      }
    }
    __syncthreads();
    unsigned kq = eqn < 1024u ? eqn : 1024u;
    for (unsigned t = threadIdx.x; t < kq; t += 256u){
      unsigned idx = eq[t], rank = 0u;
      for (unsigned j = 0; j < kq; j++) if (eq[j] < idx) rank++;
      if (rank == remF - 1u){ st[base+4] = T; st[base+5] = idx; }
    }
    __syncthreads();
  }
}

// --------- fused: candidacy map + dense gumbel + score hist ---------------
__device__ __forceinline__ float gumbel_score(uint32_t kk0, uint32_t kk1, uint32_t i, float prob){
  uint32_t y0, y1; threefry2x32(kk0, kk1, 0u, i, y0, y1);
  uint32_t bits = y0 ^ y1;                       // partitionable 32-bit fold
  float f = __uint_as_float((bits >> 9) | 0x3F800000u) - 1.0f;
  float u = fmaxf(1e-12f, f + 1e-12f);
  float l1 = (float)log((double)u);              // jnp.log(u)       (f32-rounded)
  float l2 = (float)log((double)(-l1));          // jnp.log(-log(u)) (f32-rounded)
  float lp = (float)log((double)prob);           // jnp.log(probs)   (f32-rounded)
  return lp - l2;
}

// 1024 blocks x 1024 thr, 16384 elems/block. LDS 40KB, VGPR<=128 -> 16 waves/CU.
__global__ __launch_bounds__(1024, 4) void k_map_gumbel(
    const float4* __restrict__ cam4, const int4* __restrict__ roi4,
    unsigned* __restrict__ st,
    unsigned long long* __restrict__ LA, unsigned long long* __restrict__ LB,
    unsigned* __restrict__ sh1a, unsigned* __restrict__ sh1b,
    uint32_t kf0, uint32_t kf1, uint32_t kb0, uint32_t kb1){
  __shared__ unsigned long long bufA[2048], bufB[2048];   // 32 KB (prob,idx)
  __shared__ unsigned la[1024], lb[1024];                 // 8 KB score hists
  __shared__ unsigned nA_s, nB_s, bA_s, bB_s;
  if (threadIdx.x < 1024u){ la[threadIdx.x] = 0u; lb[threadIdx.x] = 0u; }
  if (threadIdx.x == 0){ nA_s = 0u; nB_s = 0u; }
  unsigned Ta = st[12], ca = st[13];
  unsigned Tb = st[20], cb = st[21];
  const unsigned OKEPS = okey(1e-8f);
  __syncthreads();
  unsigned base = blockIdx.x * 4096u;   // float4 units; block covers 16384 elems
  for (int j = 0; j < 4; j++){
    unsigned u = base + threadIdx.x + (unsigned)j*1024u;
    float4 c = cam4[u]; int4 r = roi4[u];
#define MG(cc, rr, kk) { unsigned i = 4u*u + (kk); \
    float vbg = (cc) + 1e-8f; \
    unsigned okb = okey(vbg); \
    unsigned okf = (rr) ? okb : OKEPS; \
    if (okf > Ta || (okf == Ta && i <= ca)){ \
      float prob = (rr) ? vbg : 1e-8f; \
      unsigned p = wave_reserve_lds(&nA_s); \
      if (p < 2048u) bufA[p] = ((unsigned long long)__float_as_uint(prob) << 32) | i; } \
    if (okb < Tb || (okb == Tb && i <= cb)){ \
      float pb2 = fmaxf(1.0f - vbg, 0.0f) + 1e-8f; \
      unsigned p = wave_reserve_lds(&nB_s); \
      if (p < 2048u) bufB[p] = ((unsigned long long)__float_as_uint(pb2) << 32) | i; } }
    MG(c.x, r.x, 0u) MG(c.y, r.y, 1u) MG(c.z, r.z, 2u) MG(c.w, r.w, 3u)
#undef MG
  }
  __syncthreads();
  if (threadIdx.x == 0){
    unsigned tA = nA_s < 2048u ? nA_s : 2048u;
    unsigned tB = nB_s < 2048u ? nB_s : 2048u;
    nA_s = tA; nB_s = tB;
    bA_s = atomicAdd(&st[48], tA); bB_s = atomicAdd(&st[49], tB);
  }
  __syncthreads();
  for (unsigned e = threadIdx.x; e < nA_s; e += 1024u){
    unsigned long long v = bufA[e];
    unsigned i = (unsigned)v;
    float prob = __uint_as_float((unsigned)(v >> 32));
    float s = gumbel_score(kf0, kf1, i, prob);
    unsigned p = bA_s + e;
    if (p < LIST_CAP) LA[p] = ((unsigned long long)okey(s) << 32) | i;
    atomicAdd(&la[sbin(s)], 1u);
  }
  for (unsigned e = threadIdx.x; e < nB_s; e += 1024u){
    unsigned long long v = bufB[e];
    unsigned i = (unsigned)v;
    float prob = __uint_as_float((unsigned)(v >> 32));
    float s = gumbel_score(kb0, kb1, i, prob);
    unsigned p = bB_s + e;
    if (p < LIST_CAP) LB[p] = ((unsigned long long)okey(s) << 32) | i;
    atomicAdd(&lb[sbin(s)], 1u);
  }
  __syncthreads();
  if (threadIdx.x < 1024u){
    unsigned va = la[threadIdx.x], vb = lb[threadIdx.x];
    if (va) atomicAdd(&sh1a[threadIdx.x], va);
    if (vb) atomicAdd(&sh1b[threadIdx.x], vb);
  }
}

// --- collect score tie-bucket (inline fin1 recompute; LDS-buffered) -------
__global__ __launch_bounds__(1024) void k_collect_s(
    const unsigned long long* __restrict__ LA, const unsigned long long* __restrict__ LB,
    const unsigned* __restrict__ sh1a, const unsigned* __restrict__ sh1b,
    unsigned* __restrict__ st,
    unsigned long long* __restrict__ colA, unsigned long long* __restrict__ colB,
    unsigned* __restrict__ ccnt){
  __shared__ unsigned long long bufA[512], bufB[512];
  __shared__ unsigned nA_s, nB_s, bA_s, bB_s;
  unsigned selA, remA, selB, remB;
  block_select1024(sh1a, 5000u, true, &selA, &remA);
  block_select1024(sh1b, 5000u, true, &selB, &remB);
  if (blockIdx.x == 0 && threadIdx.x == 0){
    st[24] = selA; st[25] = remA; st[32] = selB; st[33] = remB;
  }
  if (threadIdx.x == 0){ nA_s = 0u; nB_s = 0u; }
  __syncthreads();
  unsigned mA = st[48] < LIST_CAP ? st[48] : LIST_CAP;
  unsigned mB = st[49] < LIST_CAP ? st[49] : LIST_CAP;
  unsigned tid = blockIdx.x*1024u + threadIdx.x;
  unsigned stride = gridDim.x*1024u;
  for (unsigned e = tid; e < mA; e += stride){
    unsigned long long v = LA[e];
    if (sbin(inv_okey((unsigned)(v >> 32))) == selA){
      unsigned p = wave_reserve_lds(&nA_s);
      if (p < 512u) bufA[p] = v;
    }
  }
  for (unsigned e = tid; e < mB; e += stride){
    unsigned long long v = LB[e];
    if (sbin(inv_okey((unsigned)(v >> 32))) == selB){
      unsigned p = wave_reserve_lds(&nB_s);
      if (p < 512u) bufB[p] = v;
    }
  }
  __syncthreads();
  if (threadIdx.x == 0){
    unsigned tA = nA_s < 512u ? nA_s : 512u;
    unsigned tB = nB_s < 512u ? nB_s : 512u;
    nA_s = tA; nB_s = tB;
    bA_s = atomicAdd(&ccnt[0], tA); bB_s = atomicAdd(&ccnt[1], tB);
  }
  __syncthreads();
  for (unsigned t = threadIdx.x; t < nA_s; t += 1024u)
    if (bA_s + t < COL_CAP) colA[bA_s + t] = bufA[t];
  for (unsigned t = threadIdx.x; t < nB_s; t += 1024u)
    if (bB_s + t < COL_CAP) colB[bB_s + t] = bufB[t];
}

// --------- extract exact 5000+5000 winner indices (LDS-buffered) ----------
__global__ __launch_bounds__(1024) void k_winners(
    const unsigned long long* __restrict__ LA, const unsigned long long* __restrict__ LB,
    unsigned* __restrict__ st,
    unsigned* __restrict__ winA, unsigned* __restrict__ winB){
  __shared__ unsigned bufA[256], bufB[256];
  __shared__ unsigned nA_s, nB_s, bA_s, bB_s;
  if (threadIdx.x == 0){ nA_s = 0u; nB_s = 0u; }
  __syncthreads();
  unsigned Ta = st[28], ca = st[29];
  unsigned Tb = st[36], cb = st[37];
  unsigned mA = st[48] < LIST_CAP ? st[48] : LIST_CAP;
  unsigned mB = st[49] < LIST_CAP ? st[49] : LIST_CAP;
  unsigned tid = blockIdx.x*1024u + threadIdx.x;
  unsigned stride = gridDim.x*1024u;
  for (unsigned e = tid; e < mA; e += stride){
    unsigned long long v = LA[e];
    unsigned k = (unsigned)(v >> 32), i = (unsigned)v;
    if (k > Ta || (k == Ta && i <= ca)){
      unsigned p = wave_reserve_lds(&nA_s);
      if (p < 256u) bufA[p] = i;
    }
  }
  for (unsigned e = tid; e < mB; e += stride){
    unsigned long long v = LB[e];
    unsigned k = (unsigned)(v >> 32), i = (unsigned)v;
    if (k > Tb || (k == Tb && i <= cb)){
      unsigned p = wave_reserve_lds(&nB_s);
      if (p < 256u) bufB[p] = i;
    }
  }
  __syncthreads();
  if (threadIdx.x == 0){
    unsigned tA = nA_s < 256u ? nA_s : 256u;
    unsigned tB = nB_s < 256u ? nB_s : 256u;
    nA_s = tA; nB_s = tB;
    bA_s = atomicAdd(&st[50], tA); bB_s = atomicAdd(&st[51], tB);
  }
  __syncthreads();
  for (unsigned t = threadIdx.x; t < nA_s; t += 1024u)
    if (bA_s + t < WIN_CAP) winA[bA_s + t] = bufA[t];
  for (unsigned t = threadIdx.x; t < nB_s; t += 1024u)
    if (bB_s + t < WIN_CAP) winB[bB_s + t] = bufB[t];
}

__global__ void k_scatter(float* __restrict__ out,
                          const unsigned* __restrict__ winA, const unsigned* __restrict__ winB,
                          const unsigned* __restrict__ st){
  unsigned t = blockIdx.x*256u + threadIdx.x;
  unsigned nA = st[50] < WIN_CAP ? st[50] : WIN_CAP;
  unsigned nB = st[51] < WIN_CAP ? st[51] : WIN_CAP;
  if (t < nA) out[winA[t]] = 1.0f;
  if (t < nB) out[HW + winB[t]] = 1.0f;
}

extern "C" void kernel_launch(void* const* d_in, const int* in_sizes, int n_in,
                              void* d_out, int out_size, void* d_ws, size_t ws_size,
                              hipStream_t stream) {
  (void)in_sizes; (void)n_in; (void)out_size; (void)ws_size;
  const float4* cam4 = (const float4*)d_in[0];
  const int4*   roi4 = (const int4*)d_in[1];
  float* out = (float*)d_out;

  // ws layout: h1a[4096]@0 | h1b[4096]@16384 | sh1a[1024]@32768 | sh1b[1024]@36864
  //            ccnt[16]@40960 | st[64]@41024 | winA[8192]@41280 | winB[8192]@74048
  uint8_t* w = (uint8_t*)d_ws;
  unsigned* h1a  = (unsigned*)w;
  unsigned* h1b  = (unsigned*)(w + 16384);
  unsigned* sh1a = (unsigned*)(w + 32768);
  unsigned* sh1b = (unsigned*)(w + 36864);
  unsigned* ccnt = (unsigned*)(w + 40960);
  unsigned* st   = (unsigned*)(w + 41024);
  unsigned* winA = (unsigned*)(w + 41280);
  unsigned* winB = (unsigned*)(w + 74048);

  // score lists + tie-bucket collections live in d_out (128 MB scratch until
  // the final memset+scatter)
  unsigned long long* LA   = (unsigned long long*)d_out;                                 // [0,32M)
  unsigned long long* LB   = (unsigned long long*)((uint8_t*)d_out + ((size_t)32<<20));  // [32M,64M)
  unsigned long long* colA = (unsigned long long*)((uint8_t*)d_out + ((size_t)64<<20));  // 512 KB
  unsigned long long* colB = colA + COL_CAP;                                             // 512 KB

  // JAX: key(42) -> split -> k_fg, k_bg
  uint32_t kf0,kf1,kb0,kb1;
  threefry2x32(0u, 42u, 0u, 0u, kf0, kf1);
  threefry2x32(0u, 42u, 0u, 1u, kb0, kb1);

  // ---- single up-front ws zero (hists + score hists + counters + state) ----
  (void)hipMemsetAsync(w, 0, 106816, stream);

  // ---- round 0: candidate thresholds (value-binned order statistics) ----
  k_hist_val<<<512, 1024, 0, stream>>>(cam4, roi4, h1a, h1b, st);
  k_collect_cand<<<512, 1024, 0, stream>>>(cam4, roi4, h1a, h1b, st, colA, colB, ccnt);
  k_fin3<<<1, 256, 0, stream>>>(colA, colB, ccnt, st, 8, 16, 1, 0);

  // ---- round 1: fused candidacy+gumbel+score-hist, then top-5000 ----
  k_map_gumbel<<<1024, 1024, 0, stream>>>(cam4, roi4, st, LA, LB, sh1a, sh1b,
                                          kf0, kf1, kb0, kb1);
  k_collect_s<<<256, 1024, 0, stream>>>(LA, LB, sh1a, sh1b, st, colA, colB, ccnt + 2);
  k_fin3<<<1, 256, 0, stream>>>(colA, colB, ccnt + 2, st, 24, 32, 1, 1);
  k_winners<<<256, 1024, 0, stream>>>(LA, LB, st, winA, winB);

  // ---- final: zero masks + scatter winners ----
  (void)hipMemsetAsync(d_out, 0, (size_t)2*HW*4, stream);
  k_scatter<<<32, 256, 0, stream>>>(out, winA, winB, st);
}

// Round 8
// 485.025 us; speedup vs baseline: 1.4623x; 1.0457x over previous
//
#include <hip/hip_runtime.h>
#include <math.h>
#include <stdint.h>

#define HW 16777216u
#define COL_CAP  65536u              // tie-bucket collection cap, per side
#define LIST_CAP (4u*1024u*1024u)    // candidate score-list cap, per side
#define WIN_CAP  8192u

// ---------------- threefry2x32 (JAX-compatible, 20 rounds) ----------------
__host__ __device__ inline uint32_t tf_rotl(uint32_t x, int n){ return (x<<n)|(x>>(32-n)); }

__host__ __device__ inline void threefry2x32(uint32_t k0, uint32_t k1, uint32_t x0, uint32_t x1,
                                             uint32_t &o0, uint32_t &o1){
  uint32_t ks2 = k0 ^ k1 ^ 0x1BD11BDAu;
  x0 += k0; x1 += k1;
#define TF_R4(a,b,c,d) \
  x0 += x1; x1 = tf_rotl(x1,(a)); x1 ^= x0; \
  x0 += x1; x1 = tf_rotl(x1,(b)); x1 ^= x0; \
  x0 += x1; x1 = tf_rotl(x1,(c)); x1 ^= x0; \
  x0 += x1; x1 = tf_rotl(x1,(d)); x1 ^= x0;
  TF_R4(13,15,26,6)  x0 += k1;  x1 += ks2 + 1u;
  TF_R4(17,29,16,24) x0 += ks2; x1 += k0  + 2u;
  TF_R4(13,15,26,6)  x0 += k0;  x1 += k1  + 3u;
  TF_R4(17,29,16,24) x0 += k1;  x1 += ks2 + 4u;
  TF_R4(13,15,26,6)  x0 += ks2; x1 += k0  + 5u;
#undef TF_R4
  o0 = x0; o1 = x1;
}

// order-preserving uint mapping for floats (ascending)
__device__ __forceinline__ uint32_t okey(float f){
  uint32_t b = __float_as_uint(f);
  return (b & 0x80000000u) ? ~b : (b | 0x80000000u);
}
__device__ __forceinline__ float inv_okey(uint32_t k){
  uint32_t b = (k & 0x80000000u) ? (k & 0x7FFFFFFFu) : ~k;
  return __uint_as_float(b);
}

// value-domain bins (monotone in value for v>=0). cam uniform [0,1] -> ~4096/bin.
__device__ __forceinline__ unsigned vbin(float v){
  unsigned b = (unsigned)(v * 4096.0f);
  return b > 4095u ? 4095u : b;
}
// score-domain bins (1024): scores lie in ~[-3.7, 16.6); monotone affine map.
__device__ __forceinline__ unsigned sbin(float s){
  float t = (s + 4.0f) * 51.2f;
  int b = (int)t;
  b = b < 0 ? 0 : (b > 1023 ? 1023 : b);
  return (unsigned)b;
}

// wave-aggregated reserve on an LDS counter (rounds 2/5: contended GLOBAL
// atomic-with-return is ~11ns serialized — only issue it once per block).
__device__ __forceinline__ unsigned wave_reserve_lds(unsigned* cnt){
  unsigned long long m = __ballot(1);
  unsigned lane = threadIdx.x & 63u;
  unsigned leader = (unsigned)__ffsll((unsigned long long)m) - 1u;
  unsigned prefix = (unsigned)__popcll(m & ((1ull << lane) - 1ull));
  unsigned base = 0u;
  if (lane == leader) base = atomicAdd(cnt, (unsigned)__popcll(m));
  base = __shfl(base, (int)leader, 64);
  return base + prefix;
}

__device__ __forceinline__ float gumbel_score(uint32_t kk0, uint32_t kk1, uint32_t i, float prob){
  uint32_t y0, y1; threefry2x32(kk0, kk1, 0u, i, y0, y1);
  uint32_t bits = y0 ^ y1;                       // partitionable 32-bit fold
  float f = __uint_as_float((bits >> 9) | 0x3F800000u) - 1.0f;
  float u = fmaxf(1e-12f, f + 1e-12f);
  float l1 = (float)log((double)u);              // jnp.log(u)       (f32-rounded)
  float l2 = (float)log((double)(-l1));          // jnp.log(-log(u)) (f32-rounded)
  float lp = (float)log((double)prob);           // jnp.log(probs)   (f32-rounded)
  return lp - l2;
}

// st layout (u32): [0]=sum(roi)
//  fg_cand base 8 / bg_cand 16 / fg_score 24 / bg_score 32: +0 bin,+1 rem,+4 T,+5 cut
//  [48],[49] score-list counts; [50],[51] winner counts
// ccnt: [0],[1] cand tie counts; [2],[3] score tie counts

// --------- pass 1: packed value-hist (fg hi16, bg lo16) + roi sum ---------
__global__ __launch_bounds__(1024) void k_hist_val(
    const float4* __restrict__ cam4, const int4* __restrict__ roi4,
    unsigned* __restrict__ h1a, unsigned* __restrict__ h1b,
    unsigned* __restrict__ st){
  __shared__ unsigned hp[4096];
  __shared__ unsigned ssum;
  for (int j = threadIdx.x; j < 4096; j += 1024) hp[j] = 0u;
  if (threadIdx.x == 0) ssum = 0u;
  __syncthreads();
  unsigned base = blockIdx.x * 8192u;   // float4 units; block covers 32768 elems
  unsigned rs = 0u;
  for (int j = 0; j < 8; j++){
    unsigned u = base + threadIdx.x + (unsigned)j*1024u;
    float4 c = cam4[u]; int4 r = roi4[u];
#define HV(cc, rr) { unsigned b = vbin((cc) + 1e-8f); \
    atomicAdd(&hp[b], (rr) ? 0x10001u : 1u); rs += (unsigned)(rr); }
    HV(c.x, r.x) HV(c.y, r.y) HV(c.z, r.z) HV(c.w, r.w)
#undef HV
  }
  for (int o = 32; o; o >>= 1) rs += __shfl_down(rs, o, 64);
  if ((threadIdx.x & 63u) == 0u) atomicAdd(&ssum, rs);
  __syncthreads();
  for (int j = threadIdx.x; j < 4096; j += 1024){
    unsigned p = hp[j];
    if (p){
      unsigned fa = p >> 16, fb = p & 0xFFFFu;
      if (fa) atomicAdd(&h1a[j], fa);
      if (fb) atomicAdd(&h1b[j], fb);
    }
  }
  if (threadIdx.x == 0) atomicAdd(&st[0], ssum);
}

// ---- block-cooperative selects (block-size agnostic; >=256 threads) ------
__device__ void block_select4096(const unsigned* __restrict__ h, unsigned n, bool top,
                                 unsigned* out_bin, unsigned* out_rem){
  __shared__ unsigned csum[256];
  __shared__ unsigned sb, sr;
  unsigned t = threadIdx.x;
  if (t < 256u){
    unsigned s = 0u;
    #pragma unroll
    for (int j = 0; j < 16; j++) s += h[t*16 + j];
    csum[t] = s;
  }
  __syncthreads();
  if (t == 0){
    unsigned rem = n; int c;
    if (top){ for (c = 255; c >= 0; c--){ if (csum[c] >= rem) break; rem -= csum[c]; } }
    else    { for (c = 0; c < 256; c++){ if (csum[c] >= rem) break; rem -= csum[c]; } }
    int b;
    if (top){ for (b = c*16+15; b > c*16; b--){ if (h[b] >= rem) break; rem -= h[b]; } }
    else    { for (b = c*16; b < c*16+15; b++){ if (h[b] >= rem) break; rem -= h[b]; } }
    sb = (unsigned)b; sr = rem;
  }
  __syncthreads();
  *out_bin = sb; *out_rem = sr;
  __syncthreads();
}

__device__ void block_select1024(const unsigned* __restrict__ h, unsigned n, bool top,
                                 unsigned* out_bin, unsigned* out_rem){
  __shared__ unsigned csum[256];
  __shared__ unsigned sb, sr;
  unsigned t = threadIdx.x;
  if (t < 256u){
    unsigned s = 0u;
    #pragma unroll
    for (int j = 0; j < 4; j++) s += h[t*4 + j];
    csum[t] = s;
  }
  __syncthreads();
  if (t == 0){
    unsigned rem = n; int c;
    if (top){ for (c = 255; c >= 0; c--){ if (csum[c] >= rem) break; rem -= csum[c]; } }
    else    { for (c = 0; c < 256; c++){ if (csum[c] >= rem) break; rem -= csum[c]; } }
    int b;
    if (top){ for (b = c*4+3; b > c*4; b--){ if (h[b] >= rem) break; rem -= h[b]; } }
    else    { for (b = c*4; b < c*4+3; b++){ if (h[b] >= rem) break; rem -= h[b]; } }
    sb = (unsigned)b; sr = rem;
  }
  __syncthreads();
  *out_bin = sb; *out_rem = sr;
  __syncthreads();
}

// --------- pass 2 (fused): definite-candidate gumbel + tie collection -----
// Elements in bins strictly above selA (fg) / below selB (bg) are provably
// candidates (threshold lies inside the tie bin) -> gumbel now. Tie-bin
// elements go to colA/colB for exact resolution in k_fin3c.
__global__ __launch_bounds__(1024, 8) void k_collect_map(
    const float4* __restrict__ cam4, const int4* __restrict__ roi4,
    const unsigned* __restrict__ h1a, const unsigned* __restrict__ h1b,
    unsigned* __restrict__ st,
    unsigned long long* __restrict__ LA, unsigned long long* __restrict__ LB,
    unsigned long long* __restrict__ colA, unsigned long long* __restrict__ colB,
    unsigned* __restrict__ ccnt,
    unsigned* __restrict__ sh1a, unsigned* __restrict__ sh1b,
    uint32_t kf0, uint32_t kf1, uint32_t kb0, uint32_t kb1){
  __shared__ unsigned long long bufA[2560], bufB[2560];   // definite cands (prob,idx)
  __shared__ unsigned long long tieA[512], tieB[512];     // tie-bin (okey,idx)
  __shared__ unsigned la[1024], lb[1024];                 // score hists
  __shared__ unsigned nA_s, nB_s, tA_s, tB_s, bA_s, bB_s, gA_s, gB_s;
  unsigned selA, remA, selB, remB;
  unsigned nfg = (unsigned)(0.2f * (float)st[0]);  // trunc, f32 mult like jnp
  block_select4096(h1a, nfg, true, &selA, &remA);
  block_select4096(h1b, 1677721u, false, &selB, &remB);
  if (blockIdx.x == 0 && threadIdx.x == 0){
    st[8] = selA; st[9] = remA; st[16] = selB; st[17] = remB;
  }
  if (threadIdx.x < 1024u){ la[threadIdx.x] = 0u; lb[threadIdx.x] = 0u; }
  if (threadIdx.x == 0){ nA_s = 0u; nB_s = 0u; tA_s = 0u; tB_s = 0u; }
  __syncthreads();
  unsigned base = blockIdx.x * 4096u;   // 1024 blocks; 16384 elems/block
  for (int j = 0; j < 4; j++){
    unsigned u = base + threadIdx.x + (unsigned)j*1024u;
    float4 c = cam4[u]; int4 r = roi4[u];
#define KM(cc, rr, kk) { unsigned i = 4u*u + (kk); \
    float vbg = (cc) + 1e-8f; \
    unsigned bb = vbin(vbg); \
    float vfg = (rr) ? vbg : 1e-8f; \
    unsigned bf = (rr) ? bb : 0u; \
    if (bf > selA){ unsigned p = wave_reserve_lds(&nA_s); \
      if (p < 2560u) bufA[p] = ((unsigned long long)__float_as_uint(vfg) << 32) | i; } \
    else if (bf == selA){ unsigned p = wave_reserve_lds(&tA_s); \
      if (p < 512u) tieA[p] = ((unsigned long long)okey(vfg) << 32) | i; } \
    if (bb < selB){ \
      float pb2 = fmaxf(1.0f - vbg, 0.0f) + 1e-8f; \
      unsigned p = wave_reserve_lds(&nB_s); \
      if (p < 2560u) bufB[p] = ((unsigned long long)__float_as_uint(pb2) << 32) | i; } \
    else if (bb == selB){ unsigned p = wave_reserve_lds(&tB_s); \
      if (p < 512u) tieB[p] = ((unsigned long long)okey(vbg) << 32) | i; } }
    KM(c.x, r.x, 0u) KM(c.y, r.y, 1u) KM(c.z, r.z, 2u) KM(c.w, r.w, 3u)
#undef KM
  }
  __syncthreads();
  if (threadIdx.x == 0){
    nA_s = nA_s < 2560u ? nA_s : 2560u;  nB_s = nB_s < 2560u ? nB_s : 2560u;
    tA_s = tA_s < 512u  ? tA_s : 512u;   tB_s = tB_s < 512u  ? tB_s : 512u;
    bA_s = atomicAdd(&st[48], nA_s); bB_s = atomicAdd(&st[49], nB_s);
    gA_s = atomicAdd(&ccnt[0], tA_s); gB_s = atomicAdd(&ccnt[1], tB_s);
  }
  __syncthreads();
  // dense gumbel over definite candidates (full lane occupancy)
  for (unsigned e = threadIdx.x; e < nA_s; e += 1024u){
    unsigned long long v = bufA[e];
    unsigned i = (unsigned)v;
    float prob = __uint_as_float((unsigned)(v >> 32));
    float s = gumbel_score(kf0, kf1, i, prob);
    unsigned p = bA_s + e;
    if (p < LIST_CAP) LA[p] = ((unsigned long long)okey(s) << 32) | i;
    atomicAdd(&la[sbin(s)], 1u);
  }
  for (unsigned e = threadIdx.x; e < nB_s; e += 1024u){
    unsigned long long v = bufB[e];
    unsigned i = (unsigned)v;
    float prob = __uint_as_float((unsigned)(v >> 32));
    float s = gumbel_score(kb0, kb1, i, prob);
    unsigned p = bB_s + e;
    if (p < LIST_CAP) LB[p] = ((unsigned long long)okey(s) << 32) | i;
    atomicAdd(&lb[sbin(s)], 1u);
  }
  // flush tie buffers
  for (unsigned t = threadIdx.x; t < tA_s; t += 1024u)
    if (gA_s + t < COL_CAP) colA[gA_s + t] = tieA[t];
  for (unsigned t = threadIdx.x; t < tB_s; t += 1024u)
    if (gB_s + t < COL_CAP) colB[gB_s + t] = tieB[t];
  __syncthreads();
  if (threadIdx.x < 1024u){
    unsigned va = la[threadIdx.x], vb = lb[threadIdx.x];
    if (va) atomicAdd(&sh1a[threadIdx.x], va);
    if (vb) atomicAdd(&sh1b[threadIdx.x], vb);
  }
}

// --- cand tie resolve (exact radix) + gumbel fixup append (single block) --
__global__ void k_fin3c(const unsigned long long* __restrict__ colA,
                        const unsigned long long* __restrict__ colB,
                        const unsigned* __restrict__ ccnt, unsigned* __restrict__ st,
                        unsigned long long* __restrict__ LA, unsigned long long* __restrict__ LB,
                        unsigned* __restrict__ sh1a, unsigned* __restrict__ sh1b,
                        uint32_t kf0, uint32_t kf1, uint32_t kb0, uint32_t kb1){
  __shared__ unsigned h[256];
  __shared__ unsigned eq[1024];
  __shared__ unsigned long long app[6144];
  __shared__ unsigned eqn, s_pref, s_rem, napp, gbase;
  for (int side = 0; side < 2; side++){
    const unsigned long long* col = side ? colB : colA;
    int base = side ? 16 : 8;
    bool top = (side == 0);                     // fg: top, bg: bottom
    unsigned m = ccnt[side]; if (m > COL_CAP) m = COL_CAP;
    unsigned n = st[base+1];
    if (threadIdx.x == 0){ s_pref = 0u; s_rem = n; napp = 0u; }
    __syncthreads();
    for (int r = 0; r < 4; r++){
      h[threadIdx.x] = 0u;
      __syncthreads();
      unsigned pref = s_pref;
      for (unsigned e = threadIdx.x; e < m; e += 256u){
        unsigned k = (unsigned)(col[e] >> 32);
        bool act = (r == 0) || ((k >> (32 - 8*r)) == pref);
        if (act) atomicAdd(&h[(k >> (24 - 8*r)) & 0xFFu], 1u);
      }
      __syncthreads();
      if (threadIdx.x == 0){
        unsigned rem = s_rem; int b;
        if (top){ for (b = 255; b > 0; b--){ if (h[b] >= rem) break; rem -= h[b]; } }
        else    { for (b = 0; b < 255; b++){ if (h[b] >= rem) break; rem -= h[b]; } }
        s_pref = (s_pref << 8) | (unsigned)b; s_rem = rem;
      }
      __syncthreads();
    }
    unsigned T = s_pref, remF = s_rem;
    if (threadIdx.x == 0) eqn = 0u;
    __syncthreads();
    for (unsigned e = threadIdx.x; e < m; e += 256u){
      unsigned long long v = col[e];
      if ((unsigned)(v >> 32) == T){
        unsigned p = atomicAdd(&eqn, 1u);
        if (p < 1024u) eq[p] = (unsigned)v;
      }
    }
    __syncthreads();
    unsigned kq = eqn < 1024u ? eqn : 1024u;
    __shared__ unsigned s_cut;
    for (unsigned t = threadIdx.x; t < kq; t += 256u){
      unsigned idx = eq[t], rank = 0u;
      for (unsigned j = 0; j < kq; j++) if (eq[j] < idx) rank++;
      if (rank == remF - 1u){ st[base+4] = T; st[base+5] = idx; s_cut = idx; }
    }
    __syncthreads();
    unsigned cut = s_cut;
    // collect tie-bin candidates
    for (unsigned e = threadIdx.x; e < m; e += 256u){
      unsigned long long v = col[e];
      unsigned k = (unsigned)(v >> 32), i = (unsigned)v;
      bool pass = top ? (k > T || (k == T && i <= cut))
                      : (k < T || (k == T && i <= cut));
      if (pass){
        unsigned p = wave_reserve_lds(&napp);
        if (p < 6144u) app[p] = v;
      }
    }
    __syncthreads();
    if (threadIdx.x == 0){
      napp = napp < 6144u ? napp : 6144u;
      gbase = atomicAdd(&st[48 + side], napp);
    }
    __syncthreads();
    unsigned long long* L = side ? LB : LA;
    unsigned* sh = side ? sh1b : sh1a;
    for (unsigned t = threadIdx.x; t < napp; t += 256u){
      unsigned long long v = app[t];
      unsigned k = (unsigned)(v >> 32), i = (unsigned)v;
      float val = inv_okey(k);
      float prob = side ? (fmaxf(1.0f - val, 0.0f) + 1e-8f) : val;
      float s = gumbel_score(side ? kb0 : kf0, side ? kb1 : kf1, i, prob);
      unsigned p = gbase + t;
      if (p < LIST_CAP) L[p] = ((unsigned long long)okey(s) << 32) | i;
      atomicAdd(&sh[sbin(s)], 1u);
    }
    __syncthreads();
  }
}

// --- fused: definite winners + score-tie collection (one list pass) -------
__global__ __launch_bounds__(1024) void k_collect_win(
    const unsigned long long* __restrict__ LA, const unsigned long long* __restrict__ LB,
    const unsigned* __restrict__ sh1a, const unsigned* __restrict__ sh1b,
    unsigned* __restrict__ st,
    unsigned* __restrict__ winA, unsigned* __restrict__ winB,
    unsigned long long* __restrict__ wcolA, unsigned long long* __restrict__ wcolB,
    unsigned* __restrict__ ccnt){
  __shared__ unsigned long long tA[512], tB[512];
  __shared__ unsigned wA[256], wB[256];
  __shared__ unsigned nwA, nwB, ntA, ntB, bwA, bwB, btA, btB;
  unsigned selA, remA, selB, remB;
  block_select1024(sh1a, 5000u, true, &selA, &remA);
  block_select1024(sh1b, 5000u, true, &selB, &remB);
  if (blockIdx.x == 0 && threadIdx.x == 0){
    st[24] = selA; st[25] = remA; st[32] = selB; st[33] = remB;
  }
  if (threadIdx.x == 0){ nwA = 0u; nwB = 0u; ntA = 0u; ntB = 0u; }
  __syncthreads();
  unsigned mA = st[48] < LIST_CAP ? st[48] : LIST_CAP;
  unsigned mB = st[49] < LIST_CAP ? st[49] : LIST_CAP;
  unsigned tid = blockIdx.x*1024u + threadIdx.x;
  unsigned stride = gridDim.x*1024u;
  for (unsigned e = tid; e < mA; e += stride){
    unsigned long long v = LA[e];
    unsigned b = sbin(inv_okey((unsigned)(v >> 32)));
    if (b > selA){ unsigned p = wave_reserve_lds(&nwA); if (p < 256u) wA[p] = (unsigned)v; }
    else if (b == selA){ unsigned p = wave_reserve_lds(&ntA); if (p < 512u) tA[p] = v; }
  }
  for (unsigned e = tid; e < mB; e += stride){
    unsigned long long v = LB[e];
    unsigned b = sbin(inv_okey((unsigned)(v >> 32)));
    if (b > selB){ unsigned p = wave_reserve_lds(&nwB); if (p < 256u) wB[p] = (unsigned)v; }
    else if (b == selB){ unsigned p = wave_reserve_lds(&ntB); if (p < 512u) tB[p] = v; }
  }
  __syncthreads();
  if (threadIdx.x == 0){
    nwA = nwA < 256u ? nwA : 256u;  nwB = nwB < 256u ? nwB : 256u;
    ntA = ntA < 512u ? ntA : 512u;  ntB = ntB < 512u ? ntB : 512u;
    bwA = atomicAdd(&st[50], nwA); bwB = atomicAdd(&st[51], nwB);
    btA = atomicAdd(&ccnt[2], ntA); btB = atomicAdd(&ccnt[3], ntB);
  }
  __syncthreads();
  for (unsigned t = threadIdx.x; t < nwA; t += 1024u)
    if (bwA + t < WIN_CAP) winA[bwA + t] = wA[t];
  for (unsigned t = threadIdx.x; t < nwB; t += 1024u)
    if (bwB + t < WIN_CAP) winB[bwB + t] = wB[t];
  for (unsigned t = threadIdx.x; t < ntA; t += 1024u)
    if (btA + t < COL_CAP) wcolA[btA + t] = tA[t];
  for (unsigned t = threadIdx.x; t < ntB; t += 1024u)
    if (btB + t < COL_CAP) wcolB[btB + t] = tB[t];
}

// --- score tie resolve + append remaining winners (single block) ----------
__global__ void k_fin3s(const unsigned long long* __restrict__ wcolA,
                        const unsigned long long* __restrict__ wcolB,
                        const unsigned* __restrict__ ccnt, unsigned* __restrict__ st,
                        unsigned* __restrict__ winA, unsigned* __restrict__ winB){
  __shared__ unsigned h[256];
  __shared__ unsigned eq[1024];
  __shared__ unsigned app[8192];
  __shared__ unsigned eqn, s_pref, s_rem, napp, gbase, s_cut;
  for (int side = 0; side < 2; side++){
    const unsigned long long* col = side ? wcolB : wcolA;
    int base = side ? 32 : 24;
    unsigned m = ccnt[2+side]; if (m > COL_CAP) m = COL_CAP;
    unsigned n = st[base+1];
    if (threadIdx.x == 0){ s_pref = 0u; s_rem = n; napp = 0u; }
    __syncthreads();
    for (int r = 0; r < 4; r++){
      h[threadIdx.x] = 0u;
      __syncthreads();
      unsigned pref = s_pref;
      for (unsigned e = threadIdx.x; e < m; e += 256u){
        unsigned k = (unsigned)(col[e] >> 32);
        bool act = (r == 0) || ((k >> (32 - 8*r)) == pref);
        if (act) atomicAdd(&h[(k >> (24 - 8*r)) & 0xFFu], 1u);
      }
      __syncthreads();
      if (threadIdx.x == 0){
        unsigned rem = s_rem; int b;
        for (b = 255; b > 0; b--){ if (h[b] >= rem) break; rem -= h[b]; }
        s_pref = (s_pref << 8) | (unsigned)b; s_rem = rem;
      }
      __syncthreads();
    }
    unsigned T = s_pref, remF = s_rem;
    if (threadIdx.x == 0) eqn = 0u;
    __syncthreads();
    for (unsigned e = threadIdx.x; e < m; e += 256u){
      unsigned long long v = col[e];
      if ((unsigned)(v >> 32) == T){
        unsigned p = atomicAdd(&eqn, 1u);
        if (p < 1024u) eq[p] = (unsigned)v;
      }
    }
    __syncthreads();
    unsigned kq = eqn < 1024u ? eqn : 1024u;
    for (unsigned t = threadIdx.x; t < kq; t += 256u){
      unsigned idx = eq[t], rank = 0u;
      for (unsigned j = 0; j < kq; j++) if (eq[j] < idx) rank++;
      if (rank == remF - 1u){ st[base+4] = T; st[base+5] = idx; s_cut = idx; }
    }
    __syncthreads();
    unsigned cut = s_cut;
    for (unsigned e = threadIdx.x; e < m; e += 256u){
      unsigned long long v = col[e];
      unsigned k = (unsigned)(v >> 32), i = (unsigned)v;
      if (k > T || (k == T && i <= cut)){
        unsigned p = wave_reserve_lds(&napp);
        if (p < 8192u) app[p] = i;
      }
    }
    __syncthreads();
    if (threadIdx.x == 0){
      napp = napp < 8192u ? napp : 8192u;
      gbase = atomicAdd(&st[50 + side], napp);
    }
    __syncthreads();
    unsigned* win = side ? winB : winA;
    for (unsigned t = threadIdx.x; t < napp; t += 256u)
      if (gbase + t < WIN_CAP) win[gbase + t] = app[t];
    __syncthreads();
  }
}

// --------- zero masks (float4 streaming stores) + scatter winners ---------
__global__ __launch_bounds__(1024) void k_zero(float4* __restrict__ out4){
  unsigned tid = blockIdx.x*1024u + threadIdx.x;
  float4 z = {0.f, 0.f, 0.f, 0.f};
  for (int j = 0; j < 16; j++) out4[tid + (unsigned)j*524288u] = z;
}

__global__ void k_scatter(float* __restrict__ out,
                          const unsigned* __restrict__ winA, const unsigned* __restrict__ winB,
                          const unsigned* __restrict__ st){
  unsigned t = blockIdx.x*256u + threadIdx.x;
  unsigned nA = st[50] < WIN_CAP ? st[50] : WIN_CAP;
  unsigned nB = st[51] < WIN_CAP ? st[51] : WIN_CAP;
  if (t < nA) out[winA[t]] = 1.0f;
  if (t < nB) out[HW + winB[t]] = 1.0f;
}

extern "C" void kernel_launch(void* const* d_in, const int* in_sizes, int n_in,
                              void* d_out, int out_size, void* d_ws, size_t ws_size,
                              hipStream_t stream) {
  (void)in_sizes; (void)n_in; (void)out_size; (void)ws_size;
  const float4* cam4 = (const float4*)d_in[0];
  const int4*   roi4 = (const int4*)d_in[1];
  float* out = (float*)d_out;

  // ws: h1a[4096]@0 | h1b[4096]@16384 | sh1a[1024]@32768 | sh1b[1024]@36864
  //     ccnt[16]@40960 | st[64]@41024 | winA[8192]@41280 | winB[8192]@74048
  uint8_t* w = (uint8_t*)d_ws;
  unsigned* h1a  = (unsigned*)w;
  unsigned* h1b  = (unsigned*)(w + 16384);
  unsigned* sh1a = (unsigned*)(w + 32768);
  unsigned* sh1b = (unsigned*)(w + 36864);
  unsigned* ccnt = (unsigned*)(w + 40960);
  unsigned* st   = (unsigned*)(w + 41024);
  unsigned* winA = (unsigned*)(w + 41280);
  unsigned* winB = (unsigned*)(w + 74048);

  // score lists + tie collections live in d_out (scratch until k_zero)
  unsigned long long* LA    = (unsigned long long*)d_out;                                 // [0,32M)
  unsigned long long* LB    = (unsigned long long*)((uint8_t*)d_out + ((size_t)32<<20));  // [32M,64M)
  unsigned long long* colA  = (unsigned long long*)((uint8_t*)d_out + ((size_t)64<<20));
  unsigned long long* colB  = colA + COL_CAP;
  unsigned long long* wcolA = colB + COL_CAP;
  unsigned long long* wcolB = wcolA + COL_CAP;

  // JAX: key(42) -> split -> k_fg, k_bg
  uint32_t kf0,kf1,kb0,kb1;
  threefry2x32(0u, 42u, 0u, 0u, kf0, kf1);
  threefry2x32(0u, 42u, 0u, 1u, kb0, kb1);

  (void)hipMemsetAsync(w, 0, 41280, stream);   // hists + counters + state only

  // pass 1: value hists + roi sum
  k_hist_val<<<512, 1024, 0, stream>>>(cam4, roi4, h1a, h1b, st);
  // pass 2 (fused): definite-cand gumbel + tie collection
  k_collect_map<<<1024, 1024, 0, stream>>>(cam4, roi4, h1a, h1b, st, LA, LB,
                                           colA, colB, ccnt, sh1a, sh1b,
                                           kf0, kf1, kb0, kb1);
  // cand tie resolve + fixup gumbel append
  k_fin3c<<<1, 256, 0, stream>>>(colA, colB, ccnt, st, LA, LB, sh1a, sh1b,
                                 kf0, kf1, kb0, kb1);
  // one list pass: definite winners + score-tie collection
  k_collect_win<<<256, 1024, 0, stream>>>(LA, LB, sh1a, sh1b, st, winA, winB,
                                          wcolA, wcolB, ccnt);
  // score tie resolve + append remaining winners
  k_fin3s<<<1, 256, 0, stream>>>(wcolA, wcolB, ccnt, st, winA, winB);
  // zero masks + scatter
  k_zero<<<512, 1024, 0, stream>>>((float4*)d_out);
  k_scatter<<<32, 256, 0, stream>>>(out, winA, winB, st);
}